// Round 1
// baseline (464.755 us; speedup 1.0000x reference)
//
#include <hip/hip_runtime.h>
#include <math.h>

#define HN0 1373

// ---------------- fused GEMM: C0 = A@B0, C1 = A@B1, K=256, 256 cols ----------
__global__ __launch_bounds__(256) void gemm_fused(
    const float* __restrict__ A, const float* __restrict__ B0,
    const float* __restrict__ B1, float* __restrict__ C0,
    float* __restrict__ C1, int rows) {
  __shared__ __align__(16) float As[16][64];
  __shared__ __align__(16) float Bs0[16][64];
  __shared__ __align__(16) float Bs1[16][64];
  int tid = threadIdx.x;
  int tx = tid & 15, ty = tid >> 4;
  int rowBase = blockIdx.x * 64;
  int colBase = blockIdx.y * 64;
  float acc0[4][4] = {};
  float acc1[4][4] = {};
  int lrA = tid >> 2, lcA = (tid & 3) << 2;
  int krB = tid >> 4, ccB = (tid & 15) << 2;
  for (int k0 = 0; k0 < 256; k0 += 16) {
    float4 av = make_float4(0.f, 0.f, 0.f, 0.f);
    int ar = rowBase + lrA;
    if (ar < rows) av = *reinterpret_cast<const float4*>(A + (size_t)ar * 256 + k0 + lcA);
    As[lcA + 0][lrA] = av.x; As[lcA + 1][lrA] = av.y;
    As[lcA + 2][lrA] = av.z; As[lcA + 3][lrA] = av.w;
    *reinterpret_cast<float4*>(&Bs0[krB][ccB]) =
        *reinterpret_cast<const float4*>(B0 + (size_t)(k0 + krB) * 256 + colBase + ccB);
    *reinterpret_cast<float4*>(&Bs1[krB][ccB]) =
        *reinterpret_cast<const float4*>(B1 + (size_t)(k0 + krB) * 256 + colBase + ccB);
    __syncthreads();
#pragma unroll
    for (int kk = 0; kk < 16; ++kk) {
      float4 a4 = *reinterpret_cast<const float4*>(&As[kk][ty * 4]);
      float4 b4 = *reinterpret_cast<const float4*>(&Bs0[kk][tx * 4]);
      float4 c4 = *reinterpret_cast<const float4*>(&Bs1[kk][tx * 4]);
      float aa[4] = {a4.x, a4.y, a4.z, a4.w};
      float bb[4] = {b4.x, b4.y, b4.z, b4.w};
      float cc[4] = {c4.x, c4.y, c4.z, c4.w};
#pragma unroll
      for (int i = 0; i < 4; ++i)
#pragma unroll
        for (int j = 0; j < 4; ++j) {
          acc0[i][j] = fmaf(aa[i], bb[j], acc0[i][j]);
          acc1[i][j] = fmaf(aa[i], cc[j], acc1[i][j]);
        }
    }
    __syncthreads();
  }
#pragma unroll
  for (int i = 0; i < 4; ++i) {
    int r = rowBase + ty * 4 + i;
    if (r < rows) {
      float4 o0 = make_float4(acc0[i][0], acc0[i][1], acc0[i][2], acc0[i][3]);
      float4 o1 = make_float4(acc1[i][0], acc1[i][1], acc1[i][2], acc1[i][3]);
      *reinterpret_cast<float4*>(C0 + (size_t)r * 256 + colBase + tx * 4) = o0;
      *reinterpret_cast<float4*>(C1 + (size_t)r * 256 + colBase + tx * 4) = o1;
    }
  }
}

// -------- ft_attn = softmax(tanh(einsum(fs, W_prob)), axis=g); col sum-sq ----
__global__ __launch_bounds__(256) void attn_probs(
    const float* __restrict__ feat_src, const float* __restrict__ W_prob,
    float* __restrict__ ft_attn, float* __restrict__ col_ss, int N) {
  __shared__ float WL[8192];       // 8 x 32 x 32
  __shared__ float fsL[16 * 256];  // 16 nodes
  int tid = threadIdx.x;
  for (int i = tid; i < 8192; i += 256) WL[i] = W_prob[i];
  int nodeBase = blockIdx.x * 16;
  float ssp = 0.f;
  for (int i = 0; i < 16; ++i) {
    int n = nodeBase + i;
    float v = (n < N) ? feat_src[(size_t)n * 256 + tid] : 0.f;
    fsL[i * 256 + tid] = v;
    ssp += v * v;
  }
  atomicAdd(&col_ss[tid], ssp);
  __syncthreads();
  int h = tid >> 5, g = tid & 31;
  for (int i = 0; i < 16; ++i) {
    int n = nodeBase + i;
    if (n >= N) break;
    float t = 0.f;
    const float* wp = &WL[h * 1024 + g];
    const float* fr = &fsL[i * 256 + h * 32];
#pragma unroll
    for (int f = 0; f < 32; ++f) t = fmaf(fr[f], wp[f * 32], t);
    t = tanhf(t);
    float mx = t;
#pragma unroll
    for (int s = 16; s >= 1; s >>= 1) mx = fmaxf(mx, __shfl_xor(mx, s));
    float ex = expf(t - mx);
    float sm = ex;
#pragma unroll
    for (int s = 16; s >= 1; s >>= 1) sm += __shfl_xor(sm, s);
    ft_attn[(size_t)n * 256 + tid] = ex / sm;
  }
}

// --------- per-node inverse norms of sloc/topo (D=32) ------------------------
__global__ __launch_bounds__(256) void node_norms(
    const float* __restrict__ sloc, const float* __restrict__ topo,
    float* __restrict__ inv_s, float* __restrict__ inv_t, int N) {
  int node = blockIdx.x * 8 + (threadIdx.x >> 5);
  int d = threadIdx.x & 31;
  if (node >= N) return;
  float s = sloc[(size_t)node * 32 + d];
  float t = topo[(size_t)node * 32 + d];
  float ss = s * s, tt = t * t;
#pragma unroll
  for (int m = 16; m >= 1; m >>= 1) {
    ss += __shfl_xor(ss, m);
    tt += __shfl_xor(tt, m);
  }
  if (d == 0) {
    inv_s[node] = 1.f / fmaxf(sqrtf(ss), 1e-12f);
    inv_t[node] = 1.f / fmaxf(sqrtf(tt), 1e-12f);
  }
}

__global__ void finalize_cn(float* col_ss) {
  int t = threadIdx.x;
  col_ss[t] = 1.f / fmaxf(sqrtf(col_ss[t]), 1e-12f);
}

// --------------- CSR build ---------------------------------------------------
__global__ void deg_kernel(const int* __restrict__ dst, int* __restrict__ deg, int E) {
  int e = blockIdx.x * 256 + threadIdx.x;
  if (e < E) atomicAdd(&deg[dst[e]], 1);
}

__global__ __launch_bounds__(1024) void scan_kernel(const int* __restrict__ deg,
                                                    int* __restrict__ start, int n) {
  __shared__ int buf[1024];
  __shared__ int carry;
  int tid = threadIdx.x;
  if (tid == 0) carry = 0;
  __syncthreads();
  for (int base = 0; base < n; base += 1024) {
    int v = (base + tid < n) ? deg[base + tid] : 0;
    buf[tid] = v;
    __syncthreads();
    for (int off = 1; off < 1024; off <<= 1) {
      int t = (tid >= off) ? buf[tid - off] : 0;
      __syncthreads();
      buf[tid] += t;
      __syncthreads();
    }
    if (base + tid < n) start[base + tid] = carry + buf[tid] - v;
    int tot = buf[1023];
    __syncthreads();
    if (tid == 0) carry += tot;
    __syncthreads();
  }
}

__global__ void fill_kernel(const int* __restrict__ src, const int* __restrict__ dst,
                            const int* __restrict__ e_feat, const float* __restrict__ etype_attn,
                            const int* __restrict__ start, int* __restrict__ cursor,
                            int* __restrict__ csr_src, float* __restrict__ csr_w, int E) {
  int e = blockIdx.x * 256 + threadIdx.x;
  if (e >= E) return;
  int d = dst[e];
  int pos = start[d] + atomicAdd(&cursor[d], 1);
  csr_src[pos] = src[e];
  csr_w[pos] = etype_attn[e_feat[e]];
}

// --------------- main: per-dst-node online softmax + aggregation -------------
__global__ __launch_bounds__(256) void edge_aggregate(
    const float* __restrict__ feat_src, const float* __restrict__ resval,
    const float* __restrict__ ft_attn, const float* __restrict__ inv_cn,
    const float* __restrict__ sloc, const float* __restrict__ topo,
    const float* __restrict__ inv_s, const float* __restrict__ inv_t,
    const int* __restrict__ start, const int* __restrict__ deg,
    const int* __restrict__ csr_src, const float* __restrict__ csr_w,
    float* __restrict__ out, int N) {
  int n = blockIdx.x;
  int tid = threadIdx.x;
  int d = tid & 31;
  float attn_d = ft_attn[(size_t)n * 256 + tid];
  float icn = inv_cn[tid];
  float sld = sloc[(size_t)n * 32 + d] * inv_s[n];
  float tpd = topo[(size_t)n * 32 + d] * inv_t[n];
  float m = -INFINITY, l = 0.f;
  float accf = 0.f, accs = 0.f, acct = 0.f;
  int s0 = start[n], dg = deg[n];
  for (int i = 0; i < dg; ++i) {
    int sidx = csr_src[s0 + i];
    float wet = csr_w[s0 + i];
    float fs = feat_src[(size_t)sidx * 256 + tid];
    float sl = sloc[(size_t)sidx * 32 + d];
    float tp = topo[(size_t)sidx * 32 + d];
    float pa = attn_d * fs * icn;
    float cs = sl * sld;
    float ct = tp * tpd;
#pragma unroll
    for (int mm = 16; mm >= 1; mm >>= 1) {
      pa += __shfl_xor(pa, mm);
      cs += __shfl_xor(cs, mm);
      ct += __shfl_xor(ct, mm);
    }
    cs *= inv_s[sidx];
    ct *= inv_t[sidx];
    float sim = (0.4f * cs + 0.6f * ct + 1.f) * 0.5f;
    float logit = sim * pa * wet;
    float mn = fmaxf(m, logit);
    float sc = expf(m - mn);
    float p = expf(logit - mn);
    l = l * sc + p;
    accf = accf * sc + p * fs;
    accs = accs * sc + p * sl;
    acct = acct * sc + p * tp;
    m = mn;
  }
  float invl = (l > 0.f) ? 1.f / l : 0.f;
  float vf = fmaxf(accf * invl + resval[(size_t)n * 256 + tid], 0.f);
  float vs = accs * invl;
  float vt = acct * invl;
  __shared__ float rf[256], rs[256], rt[256];
  rf[tid] = vf; rs[tid] = vs; rt[tid] = vt;
  __syncthreads();
  if (tid < 32) {
    float acc = 0.f;
    for (int h = 0; h < 8; ++h) acc += rf[h * 32 + tid];
    out[(size_t)n * 32 + tid] = acc * 0.125f;
  } else if (tid < 64) {
    int j = tid - 32;
    float acc = 0.f;
    for (int h = 0; h < 8; ++h) acc += rs[h * 32 + j];
    out[(size_t)N * 32 + (size_t)n * 32 + j] = acc * 0.125f + sloc[(size_t)n * 32 + j];
  } else if (tid < 96) {
    int j = tid - 64;
    float acc = 0.f;
    for (int h = 0; h < 8; ++h) acc += rt[h * 32 + j];
    out[(size_t)2 * N * 32 + (size_t)n * 32 + j] = acc * 0.125f + topo[(size_t)n * 32 + j];
  }
}

extern "C" void kernel_launch(void* const* d_in, const int* in_sizes, int n_in,
                              void* d_out, int out_size, void* d_ws, size_t ws_size,
                              hipStream_t stream) {
  const float* feat = (const float*)d_in[0];
  const float* sloc = (const float*)d_in[1];
  const float* topo = (const float*)d_in[2];
  const int* src = (const int*)d_in[3];
  const int* dst = (const int*)d_in[4];
  const int* e_feat = (const int*)d_in[5];
  const float* W_proj0 = (const float*)d_in[6];
  const float* W_proj1 = (const float*)d_in[7];
  const float* W_prob = (const float*)d_in[8];
  const float* W_res0 = (const float*)d_in[9];
  const float* W_res1 = (const float*)d_in[10];
  const float* etype_attn = (const float*)d_in[11];
  int E = in_sizes[3];
  int N = in_sizes[1] / 32;
  float* out = (float*)d_out;

  char* ws = (char*)d_ws;
  size_t off = 0;
  auto alloc = [&](size_t bytes) -> char* {
    char* p = ws + off;
    off += (bytes + 255) & ~(size_t)255;
    return p;
  };
  int* deg = (int*)alloc((size_t)N * 4);
  int* cursor = (int*)alloc((size_t)N * 4);
  float* col_ss = (float*)alloc(256 * 4);
  int* startArr = (int*)alloc(((size_t)N + 1) * 4);
  float* inv_s = (float*)alloc((size_t)N * 4);
  float* inv_t = (float*)alloc((size_t)N * 4);
  int* csr_src = (int*)alloc((size_t)E * 4);
  float* csr_w = (float*)alloc((size_t)E * 4);
  float* feat_src = (float*)alloc((size_t)N * 256 * 4);
  float* resval = (float*)alloc((size_t)N * 256 * 4);
  float* ft_attn = (float*)alloc((size_t)N * 256 * 4);

  hipMemsetAsync(deg, 0, (size_t)N * 4, stream);
  hipMemsetAsync(cursor, 0, (size_t)N * 4, stream);
  hipMemsetAsync(col_ss, 0, 256 * 4, stream);

  int rows0 = HN0, rows1 = N - HN0;
  gemm_fused<<<dim3((rows0 + 63) / 64, 4), 256, 0, stream>>>(
      feat, W_proj0, W_res0, feat_src, resval, rows0);
  gemm_fused<<<dim3((rows1 + 63) / 64, 4), 256, 0, stream>>>(
      feat + (size_t)HN0 * 256, W_proj1, W_res1,
      feat_src + (size_t)HN0 * 256, resval + (size_t)HN0 * 256, rows1);

  node_norms<<<(N + 7) / 8, 256, 0, stream>>>(sloc, topo, inv_s, inv_t, N);
  attn_probs<<<(N + 15) / 16, 256, 0, stream>>>(feat_src, W_prob, ft_attn, col_ss, N);
  finalize_cn<<<1, 256, 0, stream>>>(col_ss);

  deg_kernel<<<(E + 255) / 256, 256, 0, stream>>>(dst, deg, E);
  scan_kernel<<<1, 1024, 0, stream>>>(deg, startArr, N);
  fill_kernel<<<(E + 255) / 256, 256, 0, stream>>>(src, dst, e_feat, etype_attn,
                                                   startArr, cursor, csr_src, csr_w, E);

  edge_aggregate<<<N, 256, 0, stream>>>(feat_src, resval, ft_attn, col_ss, sloc, topo,
                                        inv_s, inv_t, startArr, deg, csr_src, csr_w, out, N);
}

// Round 2
// 336.475 us; speedup vs baseline: 1.3812x; 1.3812x over previous
//
#include <hip/hip_runtime.h>
#include <math.h>

#define HN0 1373
#define NEG_BIG -1e30f

// ---------------- fused GEMM: C0 = A@B0, C1 = A@B1, K=256, 256 cols ----------
__global__ __launch_bounds__(256) void gemm_fused(
    const float* __restrict__ A, const float* __restrict__ B0,
    const float* __restrict__ B1, float* __restrict__ C0,
    float* __restrict__ C1, int rows) {
  __shared__ __align__(16) float As[16][64];
  __shared__ __align__(16) float Bs0[16][64];
  __shared__ __align__(16) float Bs1[16][64];
  int tid = threadIdx.x;
  int tx = tid & 15, ty = tid >> 4;
  int rowBase = blockIdx.x * 64;
  int colBase = blockIdx.y * 64;
  float acc0[4][4] = {};
  float acc1[4][4] = {};
  int lrA = tid >> 2, lcA = (tid & 3) << 2;
  int krB = tid >> 4, ccB = (tid & 15) << 2;
  for (int k0 = 0; k0 < 256; k0 += 16) {
    float4 av = make_float4(0.f, 0.f, 0.f, 0.f);
    int ar = rowBase + lrA;
    if (ar < rows) av = *reinterpret_cast<const float4*>(A + (size_t)ar * 256 + k0 + lcA);
    As[lcA + 0][lrA] = av.x; As[lcA + 1][lrA] = av.y;
    As[lcA + 2][lrA] = av.z; As[lcA + 3][lrA] = av.w;
    *reinterpret_cast<float4*>(&Bs0[krB][ccB]) =
        *reinterpret_cast<const float4*>(B0 + (size_t)(k0 + krB) * 256 + colBase + ccB);
    *reinterpret_cast<float4*>(&Bs1[krB][ccB]) =
        *reinterpret_cast<const float4*>(B1 + (size_t)(k0 + krB) * 256 + colBase + ccB);
    __syncthreads();
#pragma unroll
    for (int kk = 0; kk < 16; ++kk) {
      float4 a4 = *reinterpret_cast<const float4*>(&As[kk][ty * 4]);
      float4 b4 = *reinterpret_cast<const float4*>(&Bs0[kk][tx * 4]);
      float4 c4 = *reinterpret_cast<const float4*>(&Bs1[kk][tx * 4]);
      float aa[4] = {a4.x, a4.y, a4.z, a4.w};
      float bb[4] = {b4.x, b4.y, b4.z, b4.w};
      float cc[4] = {c4.x, c4.y, c4.z, c4.w};
#pragma unroll
      for (int i = 0; i < 4; ++i)
#pragma unroll
        for (int j = 0; j < 4; ++j) {
          acc0[i][j] = fmaf(aa[i], bb[j], acc0[i][j]);
          acc1[i][j] = fmaf(aa[i], cc[j], acc1[i][j]);
        }
    }
    __syncthreads();
  }
#pragma unroll
  for (int i = 0; i < 4; ++i) {
    int r = rowBase + ty * 4 + i;
    if (r < rows) {
      float4 o0 = make_float4(acc0[i][0], acc0[i][1], acc0[i][2], acc0[i][3]);
      float4 o1 = make_float4(acc1[i][0], acc1[i][1], acc1[i][2], acc1[i][3]);
      *reinterpret_cast<float4*>(C0 + (size_t)r * 256 + colBase + tx * 4) = o0;
      *reinterpret_cast<float4*>(C1 + (size_t)r * 256 + colBase + tx * 4) = o1;
    }
  }
}

// -------- ft_attn = softmax(tanh(einsum(fs, W_prob)), axis=g); col sum-sq ----
__global__ __launch_bounds__(256) void attn_probs(
    const float* __restrict__ feat_src, const float* __restrict__ W_prob,
    float* __restrict__ ft_attn, float* __restrict__ col_ss, int N) {
  __shared__ float WL[8192];       // 8 x 32 x 32
  __shared__ float fsL[16 * 256];  // 16 nodes
  int tid = threadIdx.x;
  for (int i = tid; i < 8192; i += 256) WL[i] = W_prob[i];
  int nodeBase = blockIdx.x * 16;
  float ssp = 0.f;
  for (int i = 0; i < 16; ++i) {
    int n = nodeBase + i;
    float v = (n < N) ? feat_src[(size_t)n * 256 + tid] : 0.f;
    fsL[i * 256 + tid] = v;
    ssp += v * v;
  }
  atomicAdd(&col_ss[tid], ssp);
  __syncthreads();
  int h = tid >> 5, g = tid & 31;
  for (int i = 0; i < 16; ++i) {
    int n = nodeBase + i;
    if (n >= N) break;
    float t = 0.f;
    const float* wp = &WL[h * 1024 + g];
    const float* fr = &fsL[i * 256 + h * 32];
#pragma unroll
    for (int f = 0; f < 32; ++f) t = fmaf(fr[f], wp[f * 32], t);
    t = tanhf(t);
    float mx = t;
#pragma unroll
    for (int s = 16; s >= 1; s >>= 1) mx = fmaxf(mx, __shfl_xor(mx, s));
    float ex = __expf(t - mx);
    float sm = ex;
#pragma unroll
    for (int s = 16; s >= 1; s >>= 1) sm += __shfl_xor(sm, s);
    ft_attn[(size_t)n * 256 + tid] = ex / sm;
  }
}

// --------- per-node inverse norms of sloc/topo (D=32) ------------------------
__global__ __launch_bounds__(256) void node_norms(
    const float* __restrict__ sloc, const float* __restrict__ topo,
    float* __restrict__ inv_s, float* __restrict__ inv_t, int N) {
  int node = blockIdx.x * 8 + (threadIdx.x >> 5);
  int d = threadIdx.x & 31;
  if (node >= N) return;
  float s = sloc[(size_t)node * 32 + d];
  float t = topo[(size_t)node * 32 + d];
  float ss = s * s, tt = t * t;
#pragma unroll
  for (int m = 16; m >= 1; m >>= 1) {
    ss += __shfl_xor(ss, m);
    tt += __shfl_xor(tt, m);
  }
  if (d == 0) {
    inv_s[node] = 1.f / fmaxf(sqrtf(ss), 1e-12f);
    inv_t[node] = 1.f / fmaxf(sqrtf(tt), 1e-12f);
  }
}

__global__ void finalize_cn(float* col_ss) {
  int t = threadIdx.x;
  col_ss[t] = 1.f / fmaxf(sqrtf(col_ss[t]), 1e-12f);
}

// --------------- per-edge sim * etype weight ---------------------------------
// 8 lanes per edge, float4 over D=32.
__global__ __launch_bounds__(256) void edge_sim(
    const int* __restrict__ src, const int* __restrict__ dst,
    const int* __restrict__ e_feat, const float* __restrict__ etype_attn,
    const float* __restrict__ sloc, const float* __restrict__ topo,
    const float* __restrict__ inv_s, const float* __restrict__ inv_t,
    float* __restrict__ simw, int E) {
  int tid = threadIdx.x;
  int j = tid & 7;
  int e = blockIdx.x * 32 + (tid >> 3);
  if (e >= E) return;
  int s = src[e], d = dst[e];
  float4 ss4 = *reinterpret_cast<const float4*>(sloc + (size_t)s * 32 + j * 4);
  float4 sd4 = *reinterpret_cast<const float4*>(sloc + (size_t)d * 32 + j * 4);
  float4 ts4 = *reinterpret_cast<const float4*>(topo + (size_t)s * 32 + j * 4);
  float4 td4 = *reinterpret_cast<const float4*>(topo + (size_t)d * 32 + j * 4);
  float cs = ss4.x * sd4.x + ss4.y * sd4.y + ss4.z * sd4.z + ss4.w * sd4.w;
  float ct = ts4.x * td4.x + ts4.y * td4.y + ts4.z * td4.z + ts4.w * td4.w;
#pragma unroll
  for (int m = 4; m >= 1; m >>= 1) {
    cs += __shfl_xor(cs, m);
    ct += __shfl_xor(ct, m);
  }
  if (j == 0) {
    cs *= inv_s[s] * inv_s[d];
    ct *= inv_t[s] * inv_t[d];
    float sim = (0.4f * cs + 0.6f * ct + 1.f) * 0.5f;
    simw[e] = sim * etype_attn[e_feat[e]];
  }
}

// --------------- CSR build ---------------------------------------------------
__global__ void deg_kernel(const int* __restrict__ dst, int* __restrict__ deg, int E) {
  int e = blockIdx.x * 256 + threadIdx.x;
  if (e < E) atomicAdd(&deg[dst[e]], 1);
}

__global__ __launch_bounds__(1024) void scan_kernel(const int* __restrict__ deg,
                                                    int* __restrict__ start, int n) {
  __shared__ int buf[1024];
  __shared__ int carry;
  int tid = threadIdx.x;
  if (tid == 0) carry = 0;
  __syncthreads();
  for (int base = 0; base < n; base += 1024) {
    int v = (base + tid < n) ? deg[base + tid] : 0;
    buf[tid] = v;
    __syncthreads();
    for (int off = 1; off < 1024; off <<= 1) {
      int t = (tid >= off) ? buf[tid - off] : 0;
      __syncthreads();
      buf[tid] += t;
      __syncthreads();
    }
    if (base + tid < n) start[base + tid] = carry + buf[tid] - v;
    int tot = buf[1023];
    __syncthreads();
    if (tid == 0) carry += tot;
    __syncthreads();
  }
}

__global__ void fill_kernel(const int* __restrict__ src, const int* __restrict__ dst,
                            const float* __restrict__ simw,
                            const int* __restrict__ start, int* __restrict__ cursor,
                            int* __restrict__ csr_src, float* __restrict__ csr_w, int E) {
  int e = blockIdx.x * 256 + threadIdx.x;
  if (e >= E) return;
  int d = dst[e];
  int pos = start[d] + atomicAdd(&cursor[d], 1);
  csr_src[pos] = src[e];
  csr_w[pos] = simw[e];
}

// --------------- main: one wave per dst node, 8 heads x 8 lanes x float4 -----
__global__ __launch_bounds__(256) void edge_aggregate(
    const float* __restrict__ feat_src, const float* __restrict__ resval,
    const float* __restrict__ ft_attn, const float* __restrict__ inv_cn,
    const float* __restrict__ sloc, const float* __restrict__ topo,
    const int* __restrict__ start, const int* __restrict__ deg,
    const int* __restrict__ csr_src, const float* __restrict__ csr_w,
    float* __restrict__ out, int N) {
  int wave = threadIdx.x >> 6;
  int n = blockIdx.x * 4 + wave;
  if (n >= N) return;
  int lane = threadIdx.x & 63;
  int j = lane & 7;          // lane within head group
  int fb = (lane >> 3) * 32 + j * 4;  // feature index base (h*32 + j*4)
  int db = j * 4;            // d base within 32

  float4 attn4 = *reinterpret_cast<const float4*>(ft_attn + (size_t)n * 256 + fb);
  float4 icn4 = *reinterpret_cast<const float4*>(inv_cn + fb);
  float4 ai4 = make_float4(attn4.x * icn4.x, attn4.y * icn4.y,
                           attn4.z * icn4.z, attn4.w * icn4.w);
  float m = NEG_BIG, l = 0.f;
  float4 accf = make_float4(0.f, 0.f, 0.f, 0.f);
  float4 accs = make_float4(0.f, 0.f, 0.f, 0.f);
  float4 acct = make_float4(0.f, 0.f, 0.f, 0.f);
  int s0 = start[n], dg = deg[n];
  for (int i = 0; i < dg; ++i) {
    int sidx = csr_src[s0 + i];
    float simw = csr_w[s0 + i];
    float4 fs4 = *reinterpret_cast<const float4*>(feat_src + (size_t)sidx * 256 + fb);
    float4 sl4 = *reinterpret_cast<const float4*>(sloc + (size_t)sidx * 32 + db);
    float4 tp4 = *reinterpret_cast<const float4*>(topo + (size_t)sidx * 32 + db);
    float pa = ai4.x * fs4.x + ai4.y * fs4.y + ai4.z * fs4.z + ai4.w * fs4.w;
    pa += __shfl_xor(pa, 1);
    pa += __shfl_xor(pa, 2);
    pa += __shfl_xor(pa, 4);
    float logit = pa * simw;
    float mn = fmaxf(m, logit);
    float sc = __expf(m - mn);
    float p = __expf(logit - mn);
    l = l * sc + p;
    accf.x = fmaf(accf.x, sc, p * fs4.x);
    accf.y = fmaf(accf.y, sc, p * fs4.y);
    accf.z = fmaf(accf.z, sc, p * fs4.z);
    accf.w = fmaf(accf.w, sc, p * fs4.w);
    accs.x = fmaf(accs.x, sc, p * sl4.x);
    accs.y = fmaf(accs.y, sc, p * sl4.y);
    accs.z = fmaf(accs.z, sc, p * sl4.z);
    accs.w = fmaf(accs.w, sc, p * sl4.w);
    acct.x = fmaf(acct.x, sc, p * tp4.x);
    acct.y = fmaf(acct.y, sc, p * tp4.y);
    acct.z = fmaf(acct.z, sc, p * tp4.z);
    acct.w = fmaf(acct.w, sc, p * tp4.w);
    m = mn;
  }
  float invl = (l > 0.f) ? 1.f / l : 0.f;

  float4 res4 = *reinterpret_cast<const float4*>(resval + (size_t)n * 256 + fb);
  float4 of = make_float4(fmaxf(fmaf(accf.x, invl, res4.x), 0.f),
                          fmaxf(fmaf(accf.y, invl, res4.y), 0.f),
                          fmaxf(fmaf(accf.z, invl, res4.z), 0.f),
                          fmaxf(fmaf(accf.w, invl, res4.w), 0.f));
  float4 os = make_float4(accs.x * invl, accs.y * invl, accs.z * invl, accs.w * invl);
  float4 ot = make_float4(acct.x * invl, acct.y * invl, acct.z * invl, acct.w * invl);
  // reduce across heads: lanes differing in bits 3,4,5
#pragma unroll
  for (int msk = 8; msk <= 32; msk <<= 1) {
    of.x += __shfl_xor(of.x, msk); of.y += __shfl_xor(of.y, msk);
    of.z += __shfl_xor(of.z, msk); of.w += __shfl_xor(of.w, msk);
    os.x += __shfl_xor(os.x, msk); os.y += __shfl_xor(os.y, msk);
    os.z += __shfl_xor(os.z, msk); os.w += __shfl_xor(os.w, msk);
    ot.x += __shfl_xor(ot.x, msk); ot.y += __shfl_xor(ot.y, msk);
    ot.z += __shfl_xor(ot.z, msk); ot.w += __shfl_xor(ot.w, msk);
  }
  if (lane < 8) {
    float4 sln = *reinterpret_cast<const float4*>(sloc + (size_t)n * 32 + db);
    float4 tpn = *reinterpret_cast<const float4*>(topo + (size_t)n * 32 + db);
    float4 o0 = make_float4(of.x * 0.125f, of.y * 0.125f, of.z * 0.125f, of.w * 0.125f);
    float4 o1 = make_float4(fmaf(os.x, 0.125f, sln.x), fmaf(os.y, 0.125f, sln.y),
                            fmaf(os.z, 0.125f, sln.z), fmaf(os.w, 0.125f, sln.w));
    float4 o2 = make_float4(fmaf(ot.x, 0.125f, tpn.x), fmaf(ot.y, 0.125f, tpn.y),
                            fmaf(ot.z, 0.125f, tpn.z), fmaf(ot.w, 0.125f, tpn.w));
    *reinterpret_cast<float4*>(out + (size_t)n * 32 + db) = o0;
    *reinterpret_cast<float4*>(out + (size_t)N * 32 + (size_t)n * 32 + db) = o1;
    *reinterpret_cast<float4*>(out + (size_t)2 * N * 32 + (size_t)n * 32 + db) = o2;
  }
}

extern "C" void kernel_launch(void* const* d_in, const int* in_sizes, int n_in,
                              void* d_out, int out_size, void* d_ws, size_t ws_size,
                              hipStream_t stream) {
  const float* feat = (const float*)d_in[0];
  const float* sloc = (const float*)d_in[1];
  const float* topo = (const float*)d_in[2];
  const int* src = (const int*)d_in[3];
  const int* dst = (const int*)d_in[4];
  const int* e_feat = (const int*)d_in[5];
  const float* W_proj0 = (const float*)d_in[6];
  const float* W_proj1 = (const float*)d_in[7];
  const float* W_prob = (const float*)d_in[8];
  const float* W_res0 = (const float*)d_in[9];
  const float* W_res1 = (const float*)d_in[10];
  const float* etype_attn = (const float*)d_in[11];
  int E = in_sizes[3];
  int N = in_sizes[1] / 32;
  float* out = (float*)d_out;

  char* ws = (char*)d_ws;
  size_t off = 0;
  auto alloc = [&](size_t bytes) -> char* {
    char* p = ws + off;
    off += (bytes + 255) & ~(size_t)255;
    return p;
  };
  int* deg = (int*)alloc((size_t)N * 4);
  int* cursor = (int*)alloc((size_t)N * 4);
  float* col_ss = (float*)alloc(256 * 4);
  int* startArr = (int*)alloc(((size_t)N + 1) * 4);
  float* inv_s = (float*)alloc((size_t)N * 4);
  float* inv_t = (float*)alloc((size_t)N * 4);
  int* csr_src = (int*)alloc((size_t)E * 4);
  float* csr_w = (float*)alloc((size_t)E * 4);
  float* simw = (float*)alloc((size_t)E * 4);
  float* feat_src = (float*)alloc((size_t)N * 256 * 4);
  float* resval = (float*)alloc((size_t)N * 256 * 4);
  float* ft_attn = (float*)alloc((size_t)N * 256 * 4);

  hipMemsetAsync(deg, 0, (size_t)N * 4, stream);
  hipMemsetAsync(cursor, 0, (size_t)N * 4, stream);
  hipMemsetAsync(col_ss, 0, 256 * 4, stream);

  int rows0 = HN0, rows1 = N - HN0;
  gemm_fused<<<dim3((rows0 + 63) / 64, 4), 256, 0, stream>>>(
      feat, W_proj0, W_res0, feat_src, resval, rows0);
  gemm_fused<<<dim3((rows1 + 63) / 64, 4), 256, 0, stream>>>(
      feat + (size_t)HN0 * 256, W_proj1, W_res1,
      feat_src + (size_t)HN0 * 256, resval + (size_t)HN0 * 256, rows1);

  node_norms<<<(N + 7) / 8, 256, 0, stream>>>(sloc, topo, inv_s, inv_t, N);
  attn_probs<<<(N + 15) / 16, 256, 0, stream>>>(feat_src, W_prob, ft_attn, col_ss, N);
  finalize_cn<<<1, 256, 0, stream>>>(col_ss);

  edge_sim<<<(E + 31) / 32, 256, 0, stream>>>(src, dst, e_feat, etype_attn,
                                              sloc, topo, inv_s, inv_t, simw, E);

  deg_kernel<<<(E + 255) / 256, 256, 0, stream>>>(dst, deg, E);
  scan_kernel<<<1, 1024, 0, stream>>>(deg, startArr, N);
  fill_kernel<<<(E + 255) / 256, 256, 0, stream>>>(src, dst, simw,
                                                   startArr, cursor, csr_src, csr_w, E);

  edge_aggregate<<<(N + 3) / 4, 256, 0, stream>>>(feat_src, resval, ft_attn, col_ss,
                                                  sloc, topo, startArr, deg,
                                                  csr_src, csr_w, out, N);
}

// Round 3
// 255.802 us; speedup vs baseline: 1.8169x; 1.3154x over previous
//
#include <hip/hip_runtime.h>
#include <math.h>

#define HN0 1373
#define NEG_BIG -1e30f
#define BM 128
#define BN 128
#define BK 32
#define LDT 40  // LDS row stride in bf16 elems (80B = 5 x 16B units, coprime with 8)

typedef __attribute__((ext_vector_type(8))) short short8;
typedef __attribute__((ext_vector_type(4))) float f32x4;

__device__ inline unsigned short f2bf(float f) {
  unsigned int u = __float_as_uint(f);
  unsigned int r = (u + 0x7FFFu + ((u >> 16) & 1u)) >> 16;
  return (unsigned short)r;
}

__device__ inline uint4 pack8bf(float4 a, float4 b) {
  uint4 o;
  o.x = (unsigned)f2bf(a.x) | ((unsigned)f2bf(a.y) << 16);
  o.y = (unsigned)f2bf(a.z) | ((unsigned)f2bf(a.w) << 16);
  o.z = (unsigned)f2bf(b.x) | ((unsigned)f2bf(b.y) << 16);
  o.w = (unsigned)f2bf(b.z) | ((unsigned)f2bf(b.w) << 16);
  return o;
}

// ---- weights -> bf16 B^T: BTw[g][n][k] = W_g(k, n), n<256: proj, n>=256: res --
__global__ __launch_bounds__(256) void convert_wt(
    const float* __restrict__ Wp0, const float* __restrict__ Wr0,
    const float* __restrict__ Wp1, const float* __restrict__ Wr1,
    unsigned short* __restrict__ BTw) {
  int n = blockIdx.x;       // 0..511
  int g = blockIdx.y;       // 0..1
  int k = threadIdx.x;      // 0..255
  const float* W;
  if (g == 0) W = (n < 256) ? Wp0 : Wr0;
  else        W = (n < 256) ? Wp1 : Wr1;
  int c = n & 255;
  BTw[(size_t)g * 512 * 256 + (size_t)n * 256 + k] = f2bf(W[(size_t)k * 256 + c]);
}

// ---- MFMA GEMM: C[rows][512] = A[rows][256] @ B[256][512], both row groups ---
__global__ __launch_bounds__(256) void gemm_mfma(
    const float* __restrict__ A, const unsigned short* __restrict__ BTw,
    float* __restrict__ C0, float* __restrict__ C1, int N) {
  __shared__ __align__(16) unsigned short As[BM * LDT];
  __shared__ __align__(16) unsigned short Bs[BN * LDT];
  int tid = threadIdx.x;
  int lane = tid & 63;
  int w = tid >> 6;
  int wr = w >> 1, wc = w & 1;

  int g0t = (HN0 + BM - 1) / BM;
  int bx = blockIdx.x;
  bool g1 = bx >= g0t;
  int rowBase = g1 ? HN0 + (bx - g0t) * BM : bx * BM;
  int rowEnd = g1 ? N : HN0;
  const unsigned short* BT = BTw + (g1 ? (size_t)512 * 256 : 0);
  int colBase = blockIdx.y * BN;

  // staging: thread handles 2 chunks of 8 elems (rows r0 and r0+64)
  int r0 = tid >> 2;
  int kp = (tid & 3) << 3;
  int ar1 = min(rowBase + r0, rowEnd - 1);
  int ar2 = min(rowBase + r0 + 64, rowEnd - 1);
  const float* aP1 = A + (size_t)ar1 * 256 + kp;
  const float* aP2 = A + (size_t)ar2 * 256 + kp;
  const unsigned short* bP1 = BT + (size_t)(colBase + r0) * 256 + kp;
  const unsigned short* bP2 = bP1 + (size_t)64 * 256;
  int wo1 = r0 * LDT + kp;
  int wo2 = (r0 + 64) * LDT + kp;

  // fragment read offsets
  int q = lane >> 4;
  int fr = lane & 15;
  int aOff = (wr * 64 + fr) * LDT + q * 8;
  int bOff = (wc * 64 + fr) * LDT + q * 8;

  f32x4 acc[4][4] = {};

  float4 fa1a = *reinterpret_cast<const float4*>(aP1);
  float4 fa1b = *reinterpret_cast<const float4*>(aP1 + 4);
  float4 fa2a = *reinterpret_cast<const float4*>(aP2);
  float4 fa2b = *reinterpret_cast<const float4*>(aP2 + 4);
  uint4 rb1 = *reinterpret_cast<const uint4*>(bP1);
  uint4 rb2 = *reinterpret_cast<const uint4*>(bP2);

  for (int t = 0; t < 8; ++t) {
    *reinterpret_cast<uint4*>(&As[wo1]) = pack8bf(fa1a, fa1b);
    *reinterpret_cast<uint4*>(&As[wo2]) = pack8bf(fa2a, fa2b);
    *reinterpret_cast<uint4*>(&Bs[wo1]) = rb1;
    *reinterpret_cast<uint4*>(&Bs[wo2]) = rb2;
    __syncthreads();
    if (t < 7) {
      int ko = (t + 1) * BK;
      fa1a = *reinterpret_cast<const float4*>(aP1 + ko);
      fa1b = *reinterpret_cast<const float4*>(aP1 + ko + 4);
      fa2a = *reinterpret_cast<const float4*>(aP2 + ko);
      fa2b = *reinterpret_cast<const float4*>(aP2 + ko + 4);
      rb1 = *reinterpret_cast<const uint4*>(bP1 + ko);
      rb2 = *reinterpret_cast<const uint4*>(bP2 + ko);
    }
    short8 af[4], bf[4];
#pragma unroll
    for (int i = 0; i < 4; ++i) {
      af[i] = *reinterpret_cast<const short8*>(&As[aOff + i * 16 * LDT]);
      bf[i] = *reinterpret_cast<const short8*>(&Bs[bOff + i * 16 * LDT]);
    }
#pragma unroll
    for (int i = 0; i < 4; ++i)
#pragma unroll
      for (int j = 0; j < 4; ++j)
        acc[i][j] = __builtin_amdgcn_mfma_f32_16x16x32_bf16(af[i], bf[j], acc[i][j], 0, 0, 0);
    __syncthreads();
  }

  float* outp = (colBase < 256) ? C0 : C1;
  int cOff = colBase & 255;
#pragma unroll
  for (int i = 0; i < 4; ++i) {
    int rb = rowBase + wr * 64 + i * 16 + q * 4;
#pragma unroll
    for (int j = 0; j < 4; ++j) {
      int col = cOff + wc * 64 + j * 16 + fr;
      f32x4 v = acc[i][j];
#pragma unroll
      for (int rr = 0; rr < 4; ++rr) {
        int r = rb + rr;
        if (r < rowEnd) outp[(size_t)r * 256 + col] = v[rr];
      }
    }
  }
}

// -------- ft_attn = softmax(tanh(einsum(fs, W_prob)), axis=g); col sum-sq ----
__global__ __launch_bounds__(256) void attn_probs(
    const float* __restrict__ feat_src, const float* __restrict__ W_prob,
    float* __restrict__ ft_attn, float* __restrict__ col_ss, int N) {
  __shared__ float WL[8192];       // 8 x 32 x 32
  __shared__ float fsL[16 * 256];  // 16 nodes
  int tid = threadIdx.x;
  for (int i = tid; i < 8192; i += 256) WL[i] = W_prob[i];
  int nodeBase = blockIdx.x * 16;
  float ssp = 0.f;
  for (int i = 0; i < 16; ++i) {
    int n = nodeBase + i;
    float v = (n < N) ? feat_src[(size_t)n * 256 + tid] : 0.f;
    fsL[i * 256 + tid] = v;
    ssp += v * v;
  }
  atomicAdd(&col_ss[tid], ssp);
  __syncthreads();
  int h = tid >> 5, g = tid & 31;
  for (int i = 0; i < 16; ++i) {
    int n = nodeBase + i;
    if (n >= N) break;
    float t = 0.f;
    const float* wp = &WL[h * 1024 + g];
    const float* fr = &fsL[i * 256 + h * 32];
#pragma unroll
    for (int f = 0; f < 32; ++f) t = fmaf(fr[f], wp[f * 32], t);
    t = tanhf(t);
    float mx = t;
#pragma unroll
    for (int s = 16; s >= 1; s >>= 1) mx = fmaxf(mx, __shfl_xor(mx, s));
    float ex = __expf(t - mx);
    float sm = ex;
#pragma unroll
    for (int s = 16; s >= 1; s >>= 1) sm += __shfl_xor(sm, s);
    ft_attn[(size_t)n * 256 + tid] = ex / sm;
  }
}

// --------- per-node inverse norms of sloc/topo (D=32) ------------------------
__global__ __launch_bounds__(256) void node_norms(
    const float* __restrict__ sloc, const float* __restrict__ topo,
    float* __restrict__ inv_s, float* __restrict__ inv_t, int N) {
  int node = blockIdx.x * 8 + (threadIdx.x >> 5);
  int d = threadIdx.x & 31;
  if (node >= N) return;
  float s = sloc[(size_t)node * 32 + d];
  float t = topo[(size_t)node * 32 + d];
  float ss = s * s, tt = t * t;
#pragma unroll
  for (int m = 16; m >= 1; m >>= 1) {
    ss += __shfl_xor(ss, m);
    tt += __shfl_xor(tt, m);
  }
  if (d == 0) {
    inv_s[node] = 1.f / fmaxf(sqrtf(ss), 1e-12f);
    inv_t[node] = 1.f / fmaxf(sqrtf(tt), 1e-12f);
  }
}

__global__ void finalize_cn(float* col_ss) {
  int t = threadIdx.x;
  col_ss[t] = 1.f / fmaxf(sqrtf(col_ss[t]), 1e-12f);
}

// --------------- per-edge sim * etype weight ---------------------------------
__global__ __launch_bounds__(256) void edge_sim(
    const int* __restrict__ src, const int* __restrict__ dst,
    const int* __restrict__ e_feat, const float* __restrict__ etype_attn,
    const float* __restrict__ sloc, const float* __restrict__ topo,
    const float* __restrict__ inv_s, const float* __restrict__ inv_t,
    float* __restrict__ simw, int E) {
  int tid = threadIdx.x;
  int j = tid & 7;
  int e = blockIdx.x * 32 + (tid >> 3);
  if (e >= E) return;
  int s = src[e], d = dst[e];
  float4 ss4 = *reinterpret_cast<const float4*>(sloc + (size_t)s * 32 + j * 4);
  float4 sd4 = *reinterpret_cast<const float4*>(sloc + (size_t)d * 32 + j * 4);
  float4 ts4 = *reinterpret_cast<const float4*>(topo + (size_t)s * 32 + j * 4);
  float4 td4 = *reinterpret_cast<const float4*>(topo + (size_t)d * 32 + j * 4);
  float cs = ss4.x * sd4.x + ss4.y * sd4.y + ss4.z * sd4.z + ss4.w * sd4.w;
  float ct = ts4.x * td4.x + ts4.y * td4.y + ts4.z * td4.z + ts4.w * td4.w;
#pragma unroll
  for (int m = 4; m >= 1; m >>= 1) {
    cs += __shfl_xor(cs, m);
    ct += __shfl_xor(ct, m);
  }
  if (j == 0) {
    cs *= inv_s[s] * inv_s[d];
    ct *= inv_t[s] * inv_t[d];
    float sim = (0.4f * cs + 0.6f * ct + 1.f) * 0.5f;
    simw[e] = sim * etype_attn[e_feat[e]];
  }
}

// --------------- CSR build ---------------------------------------------------
__global__ void deg_kernel(const int* __restrict__ dst, int* __restrict__ deg, int E) {
  int e = blockIdx.x * 256 + threadIdx.x;
  if (e < E) atomicAdd(&deg[dst[e]], 1);
}

__global__ __launch_bounds__(1024) void scan_kernel(const int* __restrict__ deg,
                                                    int* __restrict__ start, int n) {
  __shared__ int buf[1024];
  __shared__ int carry;
  int tid = threadIdx.x;
  if (tid == 0) carry = 0;
  __syncthreads();
  for (int base = 0; base < n; base += 1024) {
    int v = (base + tid < n) ? deg[base + tid] : 0;
    buf[tid] = v;
    __syncthreads();
    for (int off = 1; off < 1024; off <<= 1) {
      int t = (tid >= off) ? buf[tid - off] : 0;
      __syncthreads();
      buf[tid] += t;
      __syncthreads();
    }
    if (base + tid < n) start[base + tid] = carry + buf[tid] - v;
    int tot = buf[1023];
    __syncthreads();
    if (tid == 0) carry += tot;
    __syncthreads();
  }
}

__global__ void fill_kernel(const int* __restrict__ src, const int* __restrict__ dst,
                            const float* __restrict__ simw,
                            const int* __restrict__ start, int* __restrict__ cursor,
                            int* __restrict__ csr_src, float* __restrict__ csr_w, int E) {
  int e = blockIdx.x * 256 + threadIdx.x;
  if (e >= E) return;
  int d = dst[e];
  int pos = start[d] + atomicAdd(&cursor[d], 1);
  csr_src[pos] = src[e];
  csr_w[pos] = simw[e];
}

// --------------- main: one wave per dst node, 8 heads x 8 lanes x float4 -----
__global__ __launch_bounds__(256) void edge_aggregate(
    const float* __restrict__ feat_src, const float* __restrict__ resval,
    const float* __restrict__ ft_attn, const float* __restrict__ inv_cn,
    const float* __restrict__ sloc, const float* __restrict__ topo,
    const int* __restrict__ start, const int* __restrict__ deg,
    const int* __restrict__ csr_src, const float* __restrict__ csr_w,
    float* __restrict__ out, int N) {
  int wave = threadIdx.x >> 6;
  int n = blockIdx.x * 4 + wave;
  if (n >= N) return;
  int lane = threadIdx.x & 63;
  int j = lane & 7;
  int fb = (lane >> 3) * 32 + j * 4;
  int db = j * 4;

  float4 attn4 = *reinterpret_cast<const float4*>(ft_attn + (size_t)n * 256 + fb);
  float4 icn4 = *reinterpret_cast<const float4*>(inv_cn + fb);
  float4 ai4 = make_float4(attn4.x * icn4.x, attn4.y * icn4.y,
                           attn4.z * icn4.z, attn4.w * icn4.w);
  float m = NEG_BIG, l = 0.f;
  float4 accf = make_float4(0.f, 0.f, 0.f, 0.f);
  float4 accs = make_float4(0.f, 0.f, 0.f, 0.f);
  float4 acct = make_float4(0.f, 0.f, 0.f, 0.f);
  int s0 = start[n], dg = deg[n];
  for (int i = 0; i < dg; ++i) {
    int sidx = csr_src[s0 + i];
    float simw = csr_w[s0 + i];
    float4 fs4 = *reinterpret_cast<const float4*>(feat_src + (size_t)sidx * 256 + fb);
    float4 sl4 = *reinterpret_cast<const float4*>(sloc + (size_t)sidx * 32 + db);
    float4 tp4 = *reinterpret_cast<const float4*>(topo + (size_t)sidx * 32 + db);
    float pa = ai4.x * fs4.x + ai4.y * fs4.y + ai4.z * fs4.z + ai4.w * fs4.w;
    pa += __shfl_xor(pa, 1);
    pa += __shfl_xor(pa, 2);
    pa += __shfl_xor(pa, 4);
    float logit = pa * simw;
    float mn = fmaxf(m, logit);
    float sc = __expf(m - mn);
    float p = __expf(logit - mn);
    l = l * sc + p;
    accf.x = fmaf(accf.x, sc, p * fs4.x);
    accf.y = fmaf(accf.y, sc, p * fs4.y);
    accf.z = fmaf(accf.z, sc, p * fs4.z);
    accf.w = fmaf(accf.w, sc, p * fs4.w);
    accs.x = fmaf(accs.x, sc, p * sl4.x);
    accs.y = fmaf(accs.y, sc, p * sl4.y);
    accs.z = fmaf(accs.z, sc, p * sl4.z);
    accs.w = fmaf(accs.w, sc, p * sl4.w);
    acct.x = fmaf(acct.x, sc, p * tp4.x);
    acct.y = fmaf(acct.y, sc, p * tp4.y);
    acct.z = fmaf(acct.z, sc, p * tp4.z);
    acct.w = fmaf(acct.w, sc, p * tp4.w);
    m = mn;
  }
  float invl = (l > 0.f) ? 1.f / l : 0.f;

  float4 res4 = *reinterpret_cast<const float4*>(resval + (size_t)n * 256 + fb);
  float4 of = make_float4(fmaxf(fmaf(accf.x, invl, res4.x), 0.f),
                          fmaxf(fmaf(accf.y, invl, res4.y), 0.f),
                          fmaxf(fmaf(accf.z, invl, res4.z), 0.f),
                          fmaxf(fmaf(accf.w, invl, res4.w), 0.f));
  float4 os = make_float4(accs.x * invl, accs.y * invl, accs.z * invl, accs.w * invl);
  float4 ot = make_float4(acct.x * invl, acct.y * invl, acct.z * invl, acct.w * invl);
#pragma unroll
  for (int msk = 8; msk <= 32; msk <<= 1) {
    of.x += __shfl_xor(of.x, msk); of.y += __shfl_xor(of.y, msk);
    of.z += __shfl_xor(of.z, msk); of.w += __shfl_xor(of.w, msk);
    os.x += __shfl_xor(os.x, msk); os.y += __shfl_xor(os.y, msk);
    os.z += __shfl_xor(os.z, msk); os.w += __shfl_xor(os.w, msk);
    ot.x += __shfl_xor(ot.x, msk); ot.y += __shfl_xor(ot.y, msk);
    ot.z += __shfl_xor(ot.z, msk); ot.w += __shfl_xor(ot.w, msk);
  }
  if (lane < 8) {
    float4 sln = *reinterpret_cast<const float4*>(sloc + (size_t)n * 32 + db);
    float4 tpn = *reinterpret_cast<const float4*>(topo + (size_t)n * 32 + db);
    float4 o0 = make_float4(of.x * 0.125f, of.y * 0.125f, of.z * 0.125f, of.w * 0.125f);
    float4 o1 = make_float4(fmaf(os.x, 0.125f, sln.x), fmaf(os.y, 0.125f, sln.y),
                            fmaf(os.z, 0.125f, sln.z), fmaf(os.w, 0.125f, sln.w));
    float4 o2 = make_float4(fmaf(ot.x, 0.125f, tpn.x), fmaf(ot.y, 0.125f, tpn.y),
                            fmaf(ot.z, 0.125f, tpn.z), fmaf(ot.w, 0.125f, tpn.w));
    *reinterpret_cast<float4*>(out + (size_t)n * 32 + db) = o0;
    *reinterpret_cast<float4*>(out + (size_t)N * 32 + (size_t)n * 32 + db) = o1;
    *reinterpret_cast<float4*>(out + (size_t)2 * N * 32 + (size_t)n * 32 + db) = o2;
  }
}

extern "C" void kernel_launch(void* const* d_in, const int* in_sizes, int n_in,
                              void* d_out, int out_size, void* d_ws, size_t ws_size,
                              hipStream_t stream) {
  const float* feat = (const float*)d_in[0];
  const float* sloc = (const float*)d_in[1];
  const float* topo = (const float*)d_in[2];
  const int* src = (const int*)d_in[3];
  const int* dst = (const int*)d_in[4];
  const int* e_feat = (const int*)d_in[5];
  const float* W_proj0 = (const float*)d_in[6];
  const float* W_proj1 = (const float*)d_in[7];
  const float* W_prob = (const float*)d_in[8];
  const float* W_res0 = (const float*)d_in[9];
  const float* W_res1 = (const float*)d_in[10];
  const float* etype_attn = (const float*)d_in[11];
  int E = in_sizes[3];
  int N = in_sizes[1] / 32;
  float* out = (float*)d_out;

  char* ws = (char*)d_ws;
  size_t off = 0;
  auto alloc = [&](size_t bytes) -> char* {
    char* p = ws + off;
    off += (bytes + 255) & ~(size_t)255;
    return p;
  };
  int* deg = (int*)alloc((size_t)N * 4);
  int* cursor = (int*)alloc((size_t)N * 4);
  float* col_ss = (float*)alloc(256 * 4);
  int* startArr = (int*)alloc(((size_t)N + 1) * 4);
  float* inv_s = (float*)alloc((size_t)N * 4);
  float* inv_t = (float*)alloc((size_t)N * 4);
  int* csr_src = (int*)alloc((size_t)E * 4);
  float* csr_w = (float*)alloc((size_t)E * 4);
  float* simw = (float*)alloc((size_t)E * 4);
  float* feat_src = (float*)alloc((size_t)N * 256 * 4);
  float* resval = (float*)alloc((size_t)N * 256 * 4);
  float* ft_attn = (float*)alloc((size_t)N * 256 * 4);
  unsigned short* BTw = (unsigned short*)alloc((size_t)2 * 512 * 256 * 2);

  hipMemsetAsync(deg, 0, (size_t)N * 4, stream);
  hipMemsetAsync(cursor, 0, (size_t)N * 4, stream);
  hipMemsetAsync(col_ss, 0, 256 * 4, stream);

  convert_wt<<<dim3(512, 2), 256, 0, stream>>>(W_proj0, W_res0, W_proj1, W_res1, BTw);

  int g0t = (HN0 + BM - 1) / BM;
  int g1t = (N - HN0 + BM - 1) / BM;
  gemm_mfma<<<dim3(g0t + g1t, 4), 256, 0, stream>>>(feat, BTw, feat_src, resval, N);

  node_norms<<<(N + 7) / 8, 256, 0, stream>>>(sloc, topo, inv_s, inv_t, N);
  attn_probs<<<(N + 15) / 16, 256, 0, stream>>>(feat_src, W_prob, ft_attn, col_ss, N);
  finalize_cn<<<1, 256, 0, stream>>>(col_ss);

  edge_sim<<<(E + 31) / 32, 256, 0, stream>>>(src, dst, e_feat, etype_attn,
                                              sloc, topo, inv_s, inv_t, simw, E);

  deg_kernel<<<(E + 255) / 256, 256, 0, stream>>>(dst, deg, E);
  scan_kernel<<<1, 1024, 0, stream>>>(deg, startArr, N);
  fill_kernel<<<(E + 255) / 256, 256, 0, stream>>>(src, dst, simw,
                                                   startArr, cursor, csr_src, csr_w, E);

  edge_aggregate<<<(N + 3) / 4, 256, 0, stream>>>(feat_src, resval, ft_attn, col_ss,
                                                  sloc, topo, startArr, deg,
                                                  csr_src, csr_w, out, N);
}

// Round 4
// 197.262 us; speedup vs baseline: 2.3560x; 1.2968x over previous
//
#include <hip/hip_runtime.h>
#include <math.h>

#define HN0 1373
#define NEG_BIG -1e30f
#define BM 128
#define BN 128
#define BK 32
#define LDT 40  // LDS row stride in bf16 elems (80B = 5 x 16B units)

typedef __attribute__((ext_vector_type(8))) short short8;
typedef __attribute__((ext_vector_type(4))) float f32x4;

__device__ inline unsigned short f2bf(float f) {
  unsigned int u = __float_as_uint(f);
  unsigned int r = (u + 0x7FFFu + ((u >> 16) & 1u)) >> 16;
  return (unsigned short)r;
}
__device__ inline float bflo(unsigned int u) { return __uint_as_float(u << 16); }
__device__ inline float bfhi(unsigned int u) { return __uint_as_float(u & 0xFFFF0000u); }

__device__ inline uint4 pack8bf(float4 a, float4 b) {
  uint4 o;
  o.x = (unsigned)f2bf(a.x) | ((unsigned)f2bf(a.y) << 16);
  o.y = (unsigned)f2bf(a.z) | ((unsigned)f2bf(a.w) << 16);
  o.z = (unsigned)f2bf(b.x) | ((unsigned)f2bf(b.y) << 16);
  o.w = (unsigned)f2bf(b.z) | ((unsigned)f2bf(b.w) << 16);
  return o;
}

// ---- fused prep: convert_wt (blocks 0..1023) | node_prep | deg histogram ----
__global__ __launch_bounds__(256) void prep(
    const float* __restrict__ Wp0, const float* __restrict__ Wr0,
    const float* __restrict__ Wp1, const float* __restrict__ Wr1,
    unsigned short* __restrict__ BTw,
    const float* __restrict__ sloc, const float* __restrict__ topo,
    float* __restrict__ inv_s, float* __restrict__ inv_t,
    unsigned short* __restrict__ slt,
    const int* __restrict__ dst, int* __restrict__ deg, int N, int E) {
  int b = blockIdx.x;
  int tid = threadIdx.x;
  int nodeBlocks = (N + 7) / 8;
  if (b < 1024) {
    int n = b & 511, g = b >> 9;
    const float* W;
    if (g == 0) W = (n < 256) ? Wp0 : Wr0;
    else        W = (n < 256) ? Wp1 : Wr1;
    int c = n & 255;
    BTw[(size_t)g * 512 * 256 + (size_t)n * 256 + tid] = f2bf(W[(size_t)tid * 256 + c]);
  } else if (b < 1024 + nodeBlocks) {
    int node = (b - 1024) * 8 + (tid >> 5);
    int d = tid & 31;
    if (node >= N) return;
    float s = sloc[(size_t)node * 32 + d];
    float t = topo[(size_t)node * 32 + d];
    float ss = s * s, tt = t * t;
#pragma unroll
    for (int m = 16; m >= 1; m >>= 1) {
      ss += __shfl_xor(ss, m);
      tt += __shfl_xor(tt, m);
    }
    if (d == 0) {
      inv_s[node] = 1.f / fmaxf(sqrtf(ss), 1e-12f);
      inv_t[node] = 1.f / fmaxf(sqrtf(tt), 1e-12f);
    }
    slt[(size_t)node * 64 + d] = f2bf(s);
    slt[(size_t)node * 64 + 32 + d] = f2bf(t);
  } else {
    int e = (b - 1024 - nodeBlocks) * 256 + tid;
    if (e < E) atomicAdd(&deg[dst[e]], 1);
  }
}

// ---- MFMA GEMM: cols 0..255 -> bf16 feat, cols 256..511 -> fp32 resval ------
__global__ __launch_bounds__(256) void gemm_mfma(
    const float* __restrict__ A, const unsigned short* __restrict__ BTw,
    unsigned short* __restrict__ feat_bf, float* __restrict__ resval, int N) {
  __shared__ __align__(16) unsigned short As[BM * LDT];
  __shared__ __align__(16) unsigned short Bs[BN * LDT];
  int tid = threadIdx.x;
  int lane = tid & 63;
  int w = tid >> 6;
  int wr = w >> 1, wc = w & 1;

  int g0t = (HN0 + BM - 1) / BM;
  int bx = blockIdx.x;
  bool g1 = bx >= g0t;
  int rowBase = g1 ? HN0 + (bx - g0t) * BM : bx * BM;
  int rowEnd = g1 ? N : HN0;
  const unsigned short* BT = BTw + (g1 ? (size_t)512 * 256 : 0);
  int colBase = blockIdx.y * BN;

  int r0 = tid >> 2;
  int kp = (tid & 3) << 3;
  int ar1 = min(rowBase + r0, rowEnd - 1);
  int ar2 = min(rowBase + r0 + 64, rowEnd - 1);
  const float* aP1 = A + (size_t)ar1 * 256 + kp;
  const float* aP2 = A + (size_t)ar2 * 256 + kp;
  const unsigned short* bP1 = BT + (size_t)(colBase + r0) * 256 + kp;
  const unsigned short* bP2 = bP1 + (size_t)64 * 256;
  int wo1 = r0 * LDT + kp;
  int wo2 = (r0 + 64) * LDT + kp;

  int q = lane >> 4;
  int fr = lane & 15;
  int aOff = (wr * 64 + fr) * LDT + q * 8;
  int bOff = (wc * 64 + fr) * LDT + q * 8;

  f32x4 acc[4][4] = {};

  float4 fa1a = *reinterpret_cast<const float4*>(aP1);
  float4 fa1b = *reinterpret_cast<const float4*>(aP1 + 4);
  float4 fa2a = *reinterpret_cast<const float4*>(aP2);
  float4 fa2b = *reinterpret_cast<const float4*>(aP2 + 4);
  uint4 rb1 = *reinterpret_cast<const uint4*>(bP1);
  uint4 rb2 = *reinterpret_cast<const uint4*>(bP2);

  for (int t = 0; t < 8; ++t) {
    *reinterpret_cast<uint4*>(&As[wo1]) = pack8bf(fa1a, fa1b);
    *reinterpret_cast<uint4*>(&As[wo2]) = pack8bf(fa2a, fa2b);
    *reinterpret_cast<uint4*>(&Bs[wo1]) = rb1;
    *reinterpret_cast<uint4*>(&Bs[wo2]) = rb2;
    __syncthreads();
    if (t < 7) {
      int ko = (t + 1) * BK;
      fa1a = *reinterpret_cast<const float4*>(aP1 + ko);
      fa1b = *reinterpret_cast<const float4*>(aP1 + ko + 4);
      fa2a = *reinterpret_cast<const float4*>(aP2 + ko);
      fa2b = *reinterpret_cast<const float4*>(aP2 + ko + 4);
      rb1 = *reinterpret_cast<const uint4*>(bP1 + ko);
      rb2 = *reinterpret_cast<const uint4*>(bP2 + ko);
    }
    short8 af[4], bf4[4];
#pragma unroll
    for (int i = 0; i < 4; ++i) {
      af[i] = *reinterpret_cast<const short8*>(&As[aOff + i * 16 * LDT]);
      bf4[i] = *reinterpret_cast<const short8*>(&Bs[bOff + i * 16 * LDT]);
    }
#pragma unroll
    for (int i = 0; i < 4; ++i)
#pragma unroll
      for (int j = 0; j < 4; ++j)
        acc[i][j] = __builtin_amdgcn_mfma_f32_16x16x32_bf16(af[i], bf4[j], acc[i][j], 0, 0, 0);
    __syncthreads();
  }

  if (colBase < 256) {
#pragma unroll
    for (int i = 0; i < 4; ++i) {
      int rb = rowBase + wr * 64 + i * 16 + q * 4;
#pragma unroll
      for (int j = 0; j < 4; ++j) {
        int col = colBase + wc * 64 + j * 16 + fr;
        f32x4 v = acc[i][j];
#pragma unroll
        for (int rr = 0; rr < 4; ++rr) {
          int r = rb + rr;
          if (r < rowEnd) feat_bf[(size_t)r * 256 + col] = f2bf(v[rr]);
        }
      }
    }
  } else {
    int cOff = colBase - 256;
#pragma unroll
    for (int i = 0; i < 4; ++i) {
      int rb = rowBase + wr * 64 + i * 16 + q * 4;
#pragma unroll
      for (int j = 0; j < 4; ++j) {
        int col = cOff + wc * 64 + j * 16 + fr;
        f32x4 v = acc[i][j];
#pragma unroll
        for (int rr = 0; rr < 4; ++rr) {
          int r = rb + rr;
          if (r < rowEnd) resval[(size_t)r * 256 + col] = v[rr];
        }
      }
    }
  }
}

// -------- ft_attn = softmax(tanh(einsum(fs, W_prob)), axis=g); col sum-sq ----
__global__ __launch_bounds__(256) void attn_probs(
    const unsigned short* __restrict__ feat_bf, const float* __restrict__ W_prob,
    float* __restrict__ ft_attn, float* __restrict__ col_ss, int N) {
  __shared__ float WL[8192];
  __shared__ float fsL[16 * 256];
  int tid = threadIdx.x;
  for (int i = tid; i < 8192; i += 256) WL[i] = W_prob[i];
  int nodeBase = blockIdx.x * 16;
  float ssp = 0.f;
  for (int i = 0; i < 16; ++i) {
    int n = nodeBase + i;
    float v = (n < N) ? __uint_as_float((unsigned)feat_bf[(size_t)n * 256 + tid] << 16) : 0.f;
    fsL[i * 256 + tid] = v;
    ssp += v * v;
  }
  atomicAdd(&col_ss[tid], ssp);
  __syncthreads();
  int h = tid >> 5, g = tid & 31;
  for (int i = 0; i < 16; ++i) {
    int n = nodeBase + i;
    if (n >= N) break;
    float t = 0.f;
    const float* wp = &WL[h * 1024 + g];
    const float* fr = &fsL[i * 256 + h * 32];
#pragma unroll
    for (int f = 0; f < 32; ++f) t = fmaf(fr[f], wp[f * 32], t);
    t = tanhf(t);
    float mx = t;
#pragma unroll
    for (int s = 16; s >= 1; s >>= 1) mx = fmaxf(mx, __shfl_xor(mx, s));
    float ex = __expf(t - mx);
    float sm = ex;
#pragma unroll
    for (int s = 16; s >= 1; s >>= 1) sm += __shfl_xor(sm, s);
    ft_attn[(size_t)n * 256 + tid] = ex / sm;
  }
}

// --------------- scan stage 1: per-block (512) exclusive scan ----------------
__global__ __launch_bounds__(512) void scan_block(const int* __restrict__ deg,
                                                  int* __restrict__ start,
                                                  int* __restrict__ bsum, int n) {
  __shared__ int buf[512];
  int tid = threadIdx.x;
  int gid = blockIdx.x * 512 + tid;
  int v = (gid < n) ? deg[gid] : 0;
  buf[tid] = v;
  __syncthreads();
  for (int off = 1; off < 512; off <<= 1) {
    int t = (tid >= off) ? buf[tid - off] : 0;
    __syncthreads();
    buf[tid] += t;
    __syncthreads();
  }
  if (gid < n) start[gid] = buf[tid] - v;
  if (tid == 511) bsum[blockIdx.x] = buf[511];
}

// --------------- finalize col norms + scan stage 2 (one block) ---------------
__global__ __launch_bounds__(256) void mid_small(float* __restrict__ col_ss,
                                                 int* __restrict__ bsum, int nb) {
  int tid = threadIdx.x;
  col_ss[tid] = 1.f / fmaxf(sqrtf(col_ss[tid]), 1e-12f);
  __shared__ int buf[128];
  if (tid < nb) buf[tid] = bsum[tid];
  __syncthreads();
  if (tid == 0) {
    int run = 0;
    for (int i = 0; i < nb; ++i) { int v = buf[i]; buf[i] = run; run += v; }
  }
  __syncthreads();
  if (tid < nb) bsum[tid] = buf[tid];
}

// --------------- fill CSR + inline sim (8 lanes/edge) ------------------------
__global__ __launch_bounds__(256) void fill_sim(
    const int* __restrict__ src, const int* __restrict__ dst,
    const int* __restrict__ e_feat, const float* __restrict__ etype_attn,
    const unsigned short* __restrict__ slt,
    const float* __restrict__ inv_s, const float* __restrict__ inv_t,
    const int* __restrict__ start, const int* __restrict__ bsum,
    int* __restrict__ cursor, int* __restrict__ csr_src,
    float* __restrict__ csr_w, int E) {
  int tid = threadIdx.x;
  int j = tid & 7;
  int e = blockIdx.x * 32 + (tid >> 3);
  if (e >= E) return;
  int s = src[e], d = dst[e];
  const unsigned short* ps = slt + (size_t)s * 64 + j * 4;
  const unsigned short* pd = slt + (size_t)d * 64 + j * 4;
  uint2 sa = *reinterpret_cast<const uint2*>(ps);
  uint2 sb = *reinterpret_cast<const uint2*>(pd);
  uint2 ta = *reinterpret_cast<const uint2*>(ps + 32);
  uint2 tb = *reinterpret_cast<const uint2*>(pd + 32);
  float cs = bflo(sa.x) * bflo(sb.x) + bfhi(sa.x) * bfhi(sb.x) +
             bflo(sa.y) * bflo(sb.y) + bfhi(sa.y) * bfhi(sb.y);
  float ct = bflo(ta.x) * bflo(tb.x) + bfhi(ta.x) * bfhi(tb.x) +
             bflo(ta.y) * bflo(tb.y) + bfhi(ta.y) * bfhi(tb.y);
#pragma unroll
  for (int m = 4; m >= 1; m >>= 1) {
    cs += __shfl_xor(cs, m);
    ct += __shfl_xor(ct, m);
  }
  if (j == 0) {
    cs *= inv_s[s] * inv_s[d];
    ct *= inv_t[s] * inv_t[d];
    float sim = (0.4f * cs + 0.6f * ct + 1.f) * 0.5f;
    float wv = sim * etype_attn[e_feat[e]];
    int pos = start[d] + bsum[d >> 9] + atomicAdd(&cursor[d], 1);
    csr_src[pos] = s;
    csr_w[pos] = wv;
  }
}

// --------------- main: one wave per dst node, bf16 gathers -------------------
__global__ __launch_bounds__(256) void edge_aggregate(
    const unsigned short* __restrict__ feat_bf, const float* __restrict__ resval,
    const float* __restrict__ ft_attn, const float* __restrict__ inv_cn,
    const unsigned short* __restrict__ slt,
    const float* __restrict__ sloc, const float* __restrict__ topo,
    const int* __restrict__ start, const int* __restrict__ bsum,
    const int* __restrict__ deg,
    const int* __restrict__ csr_src, const float* __restrict__ csr_w,
    float* __restrict__ out, int N) {
  int wave = threadIdx.x >> 6;
  int n = blockIdx.x * 4 + wave;
  if (n >= N) return;
  int lane = threadIdx.x & 63;
  int j = lane & 7;
  int fb = (lane >> 3) * 32 + j * 4;
  int db = j * 4;

  float4 attn4 = *reinterpret_cast<const float4*>(ft_attn + (size_t)n * 256 + fb);
  float4 icn4 = *reinterpret_cast<const float4*>(inv_cn + fb);
  float4 ai4 = make_float4(attn4.x * icn4.x, attn4.y * icn4.y,
                           attn4.z * icn4.z, attn4.w * icn4.w);
  float m = NEG_BIG, l = 0.f;
  float4 accf = make_float4(0.f, 0.f, 0.f, 0.f);
  float4 accs = make_float4(0.f, 0.f, 0.f, 0.f);
  float4 acct = make_float4(0.f, 0.f, 0.f, 0.f);
  int s0 = start[n] + bsum[n >> 9];
  int dg = deg[n];
  for (int i = 0; i < dg; ++i) {
    int sidx = csr_src[s0 + i];
    float simw = csr_w[s0 + i];
    uint2 fp = *reinterpret_cast<const uint2*>(feat_bf + (size_t)sidx * 256 + fb);
    const unsigned short* sp = slt + (size_t)sidx * 64 + db;
    uint2 slp = *reinterpret_cast<const uint2*>(sp);
    uint2 tpp = *reinterpret_cast<const uint2*>(sp + 32);
    float fs0 = bflo(fp.x), fs1 = bfhi(fp.x), fs2 = bflo(fp.y), fs3 = bfhi(fp.y);
    float sl0 = bflo(slp.x), sl1 = bfhi(slp.x), sl2 = bflo(slp.y), sl3 = bfhi(slp.y);
    float tp0 = bflo(tpp.x), tp1 = bfhi(tpp.x), tp2 = bflo(tpp.y), tp3 = bfhi(tpp.y);
    float pa = ai4.x * fs0 + ai4.y * fs1 + ai4.z * fs2 + ai4.w * fs3;
    pa += __shfl_xor(pa, 1);
    pa += __shfl_xor(pa, 2);
    pa += __shfl_xor(pa, 4);
    float logit = pa * simw;
    float mn = fmaxf(m, logit);
    float sc = __expf(m - mn);
    float p = __expf(logit - mn);
    l = l * sc + p;
    accf.x = fmaf(accf.x, sc, p * fs0);
    accf.y = fmaf(accf.y, sc, p * fs1);
    accf.z = fmaf(accf.z, sc, p * fs2);
    accf.w = fmaf(accf.w, sc, p * fs3);
    accs.x = fmaf(accs.x, sc, p * sl0);
    accs.y = fmaf(accs.y, sc, p * sl1);
    accs.z = fmaf(accs.z, sc, p * sl2);
    accs.w = fmaf(accs.w, sc, p * sl3);
    acct.x = fmaf(acct.x, sc, p * tp0);
    acct.y = fmaf(acct.y, sc, p * tp1);
    acct.z = fmaf(acct.z, sc, p * tp2);
    acct.w = fmaf(acct.w, sc, p * tp3);
    m = mn;
  }
  float invl = (l > 0.f) ? 1.f / l : 0.f;

  float4 res4 = *reinterpret_cast<const float4*>(resval + (size_t)n * 256 + fb);
  float4 of = make_float4(fmaxf(fmaf(accf.x, invl, res4.x), 0.f),
                          fmaxf(fmaf(accf.y, invl, res4.y), 0.f),
                          fmaxf(fmaf(accf.z, invl, res4.z), 0.f),
                          fmaxf(fmaf(accf.w, invl, res4.w), 0.f));
  float4 os = make_float4(accs.x * invl, accs.y * invl, accs.z * invl, accs.w * invl);
  float4 ot = make_float4(acct.x * invl, acct.y * invl, acct.z * invl, acct.w * invl);
#pragma unroll
  for (int msk = 8; msk <= 32; msk <<= 1) {
    of.x += __shfl_xor(of.x, msk); of.y += __shfl_xor(of.y, msk);
    of.z += __shfl_xor(of.z, msk); of.w += __shfl_xor(of.w, msk);
    os.x += __shfl_xor(os.x, msk); os.y += __shfl_xor(os.y, msk);
    os.z += __shfl_xor(os.z, msk); os.w += __shfl_xor(os.w, msk);
    ot.x += __shfl_xor(ot.x, msk); ot.y += __shfl_xor(ot.y, msk);
    ot.z += __shfl_xor(ot.z, msk); ot.w += __shfl_xor(ot.w, msk);
  }
  if (lane < 8) {
    float4 sln = *reinterpret_cast<const float4*>(sloc + (size_t)n * 32 + db);
    float4 tpn = *reinterpret_cast<const float4*>(topo + (size_t)n * 32 + db);
    float4 o0 = make_float4(of.x * 0.125f, of.y * 0.125f, of.z * 0.125f, of.w * 0.125f);
    float4 o1 = make_float4(fmaf(os.x, 0.125f, sln.x), fmaf(os.y, 0.125f, sln.y),
                            fmaf(os.z, 0.125f, sln.z), fmaf(os.w, 0.125f, sln.w));
    float4 o2 = make_float4(fmaf(ot.x, 0.125f, tpn.x), fmaf(ot.y, 0.125f, tpn.y),
                            fmaf(ot.z, 0.125f, tpn.z), fmaf(ot.w, 0.125f, tpn.w));
    *reinterpret_cast<float4*>(out + (size_t)n * 32 + db) = o0;
    *reinterpret_cast<float4*>(out + (size_t)N * 32 + (size_t)n * 32 + db) = o1;
    *reinterpret_cast<float4*>(out + (size_t)2 * N * 32 + (size_t)n * 32 + db) = o2;
  }
}

extern "C" void kernel_launch(void* const* d_in, const int* in_sizes, int n_in,
                              void* d_out, int out_size, void* d_ws, size_t ws_size,
                              hipStream_t stream) {
  const float* feat = (const float*)d_in[0];
  const float* sloc = (const float*)d_in[1];
  const float* topo = (const float*)d_in[2];
  const int* src = (const int*)d_in[3];
  const int* dst = (const int*)d_in[4];
  const int* e_feat = (const int*)d_in[5];
  const float* W_proj0 = (const float*)d_in[6];
  const float* W_proj1 = (const float*)d_in[7];
  const float* W_prob = (const float*)d_in[8];
  const float* W_res0 = (const float*)d_in[9];
  const float* W_res1 = (const float*)d_in[10];
  const float* etype_attn = (const float*)d_in[11];
  int E = in_sizes[3];
  int N = in_sizes[1] / 32;
  float* out = (float*)d_out;

  char* ws = (char*)d_ws;
  size_t off = 0;
  auto alloc = [&](size_t bytes) -> char* {
    char* p = ws + off;
    off += (bytes + 255) & ~(size_t)255;
    return p;
  };
  int* deg = (int*)alloc((size_t)N * 4);
  int* cursor = (int*)alloc((size_t)N * 4);
  float* col_ss = (float*)alloc(256 * 4);
  int* startArr = (int*)alloc(((size_t)N + 1) * 4);
  int* bsum = (int*)alloc(128 * 4);
  float* inv_s = (float*)alloc((size_t)N * 4);
  float* inv_t = (float*)alloc((size_t)N * 4);
  int* csr_src = (int*)alloc((size_t)E * 4);
  float* csr_w = (float*)alloc((size_t)E * 4);
  unsigned short* feat_bf = (unsigned short*)alloc((size_t)N * 256 * 2);
  unsigned short* slt = (unsigned short*)alloc((size_t)N * 64 * 2);
  float* resval = (float*)alloc((size_t)N * 256 * 4);
  float* ft_attn = (float*)alloc((size_t)N * 256 * 4);
  unsigned short* BTw = (unsigned short*)alloc((size_t)2 * 512 * 256 * 2);

  hipMemsetAsync(deg, 0, (size_t)N * 4, stream);
  hipMemsetAsync(cursor, 0, (size_t)N * 4, stream);
  hipMemsetAsync(col_ss, 0, 256 * 4, stream);

  int nodeBlocks = (N + 7) / 8;
  int degBlocks = (E + 255) / 256;
  prep<<<1024 + nodeBlocks + degBlocks, 256, 0, stream>>>(
      W_proj0, W_res0, W_proj1, W_res1, BTw, sloc, topo, inv_s, inv_t, slt,
      dst, deg, N, E);

  int g0t = (HN0 + BM - 1) / BM;
  int g1t = (N - HN0 + BM - 1) / BM;
  gemm_mfma<<<dim3(g0t + g1t, 4), 256, 0, stream>>>(feat, BTw, feat_bf, resval, N);

  attn_probs<<<(N + 15) / 16, 256, 0, stream>>>(feat_bf, W_prob, ft_attn, col_ss, N);

  int nb = (N + 511) / 512;
  scan_block<<<nb, 512, 0, stream>>>(deg, startArr, bsum, N);
  mid_small<<<1, 256, 0, stream>>>(col_ss, bsum, nb);

  fill_sim<<<(E + 31) / 32, 256, 0, stream>>>(src, dst, e_feat, etype_attn, slt,
                                              inv_s, inv_t, startArr, bsum,
                                              cursor, csr_src, csr_w, E);

  edge_aggregate<<<(N + 3) / 4, 256, 0, stream>>>(feat_bf, resval, ft_attn, col_ss,
                                                  slt, sloc, topo, startArr, bsum, deg,
                                                  csr_src, csr_w, out, N);
}

// Round 5
// 191.014 us; speedup vs baseline: 2.4331x; 1.0327x over previous
//
#include <hip/hip_runtime.h>
#include <math.h>

#define HN0 1373
#define BM 128
#define BN 128
#define BK 32
#define LDT 40  // LDS row stride in bf16 elems (80B = 5 x 16B units)

typedef __attribute__((ext_vector_type(8))) short short8;
typedef __attribute__((ext_vector_type(4))) float f32x4;

__device__ inline unsigned short f2bf(float f) {
  unsigned int u = __float_as_uint(f);
  unsigned int r = (u + 0x7FFFu + ((u >> 16) & 1u)) >> 16;
  return (unsigned short)r;
}
__device__ inline float bflo(unsigned int u) { return __uint_as_float(u << 16); }
__device__ inline float bfhi(unsigned int u) { return __uint_as_float(u & 0xFFFF0000u); }

__device__ inline uint4 pack8bf(float4 a, float4 b) {
  uint4 o;
  o.x = (unsigned)f2bf(a.x) | ((unsigned)f2bf(a.y) << 16);
  o.y = (unsigned)f2bf(a.z) | ((unsigned)f2bf(a.w) << 16);
  o.z = (unsigned)f2bf(b.x) | ((unsigned)f2bf(b.y) << 16);
  o.w = (unsigned)f2bf(b.z) | ((unsigned)f2bf(b.w) << 16);
  return o;
}

// ---- fused prep: convert_wt (blocks 0..1023) | node_prep | deg histogram ----
__global__ __launch_bounds__(256) void prep(
    const float* __restrict__ Wp0, const float* __restrict__ Wr0,
    const float* __restrict__ Wp1, const float* __restrict__ Wr1,
    unsigned short* __restrict__ BTw,
    const float* __restrict__ sloc, const float* __restrict__ topo,
    float* __restrict__ inv_s, float* __restrict__ inv_t,
    unsigned short* __restrict__ slt,
    const int* __restrict__ dst, int* __restrict__ deg, int N, int E) {
  int b = blockIdx.x;
  int tid = threadIdx.x;
  int nodeBlocks = (N + 7) / 8;
  if (b < 1024) {
    int n = b & 511, g = b >> 9;
    const float* W;
    if (g == 0) W = (n < 256) ? Wp0 : Wr0;
    else        W = (n < 256) ? Wp1 : Wr1;
    int c = n & 255;
    BTw[(size_t)g * 512 * 256 + (size_t)n * 256 + tid] = f2bf(W[(size_t)tid * 256 + c]);
  } else if (b < 1024 + nodeBlocks) {
    int node = (b - 1024) * 8 + (tid >> 5);
    int d = tid & 31;
    if (node >= N) return;
    float s = sloc[(size_t)node * 32 + d];
    float t = topo[(size_t)node * 32 + d];
    float ss = s * s, tt = t * t;
#pragma unroll
    for (int m = 16; m >= 1; m >>= 1) {
      ss += __shfl_xor(ss, m);
      tt += __shfl_xor(tt, m);
    }
    if (d == 0) {
      inv_s[node] = 1.f / fmaxf(sqrtf(ss), 1e-12f);
      inv_t[node] = 1.f / fmaxf(sqrtf(tt), 1e-12f);
    }
    slt[(size_t)node * 64 + d] = f2bf(s);
    slt[(size_t)node * 64 + 32 + d] = f2bf(t);
  } else {
    int e = (b - 1024 - nodeBlocks) * 256 + tid;
    if (e < E) atomicAdd(&deg[dst[e]], 1);
  }
}

// ---- MFMA GEMM: cols 0..255 -> bf16 feat, cols 256..511 -> fp32 resval ------
__global__ __launch_bounds__(256) void gemm_mfma(
    const float* __restrict__ A, const unsigned short* __restrict__ BTw,
    unsigned short* __restrict__ feat_bf, float* __restrict__ resval, int N) {
  __shared__ __align__(16) unsigned short As[BM * LDT];
  __shared__ __align__(16) unsigned short Bs[BN * LDT];
  int tid = threadIdx.x;
  int lane = tid & 63;
  int w = tid >> 6;
  int wr = w >> 1, wc = w & 1;

  int g0t = (HN0 + BM - 1) / BM;
  int bx = blockIdx.x;
  bool g1 = bx >= g0t;
  int rowBase = g1 ? HN0 + (bx - g0t) * BM : bx * BM;
  int rowEnd = g1 ? N : HN0;
  const unsigned short* BT = BTw + (g1 ? (size_t)512 * 256 : 0);
  int colBase = blockIdx.y * BN;

  int r0 = tid >> 2;
  int kp = (tid & 3) << 3;
  int ar1 = min(rowBase + r0, rowEnd - 1);
  int ar2 = min(rowBase + r0 + 64, rowEnd - 1);
  const float* aP1 = A + (size_t)ar1 * 256 + kp;
  const float* aP2 = A + (size_t)ar2 * 256 + kp;
  const unsigned short* bP1 = BT + (size_t)(colBase + r0) * 256 + kp;
  const unsigned short* bP2 = bP1 + (size_t)64 * 256;
  int wo1 = r0 * LDT + kp;
  int wo2 = (r0 + 64) * LDT + kp;

  int q = lane >> 4;
  int fr = lane & 15;
  int aOff = (wr * 64 + fr) * LDT + q * 8;
  int bOff = (wc * 64 + fr) * LDT + q * 8;

  f32x4 acc[4][4] = {};

  float4 fa1a = *reinterpret_cast<const float4*>(aP1);
  float4 fa1b = *reinterpret_cast<const float4*>(aP1 + 4);
  float4 fa2a = *reinterpret_cast<const float4*>(aP2);
  float4 fa2b = *reinterpret_cast<const float4*>(aP2 + 4);
  uint4 rb1 = *reinterpret_cast<const uint4*>(bP1);
  uint4 rb2 = *reinterpret_cast<const uint4*>(bP2);

  for (int t = 0; t < 8; ++t) {
    *reinterpret_cast<uint4*>(&As[wo1]) = pack8bf(fa1a, fa1b);
    *reinterpret_cast<uint4*>(&As[wo2]) = pack8bf(fa2a, fa2b);
    *reinterpret_cast<uint4*>(&Bs[wo1]) = rb1;
    *reinterpret_cast<uint4*>(&Bs[wo2]) = rb2;
    __syncthreads();
    if (t < 7) {
      int ko = (t + 1) * BK;
      fa1a = *reinterpret_cast<const float4*>(aP1 + ko);
      fa1b = *reinterpret_cast<const float4*>(aP1 + ko + 4);
      fa2a = *reinterpret_cast<const float4*>(aP2 + ko);
      fa2b = *reinterpret_cast<const float4*>(aP2 + ko + 4);
      rb1 = *reinterpret_cast<const uint4*>(bP1 + ko);
      rb2 = *reinterpret_cast<const uint4*>(bP2 + ko);
    }
    short8 af[4], bf4[4];
#pragma unroll
    for (int i = 0; i < 4; ++i) {
      af[i] = *reinterpret_cast<const short8*>(&As[aOff + i * 16 * LDT]);
      bf4[i] = *reinterpret_cast<const short8*>(&Bs[bOff + i * 16 * LDT]);
    }
#pragma unroll
    for (int i = 0; i < 4; ++i)
#pragma unroll
      for (int j = 0; j < 4; ++j)
        acc[i][j] = __builtin_amdgcn_mfma_f32_16x16x32_bf16(af[i], bf4[j], acc[i][j], 0, 0, 0);
    __syncthreads();
  }

  if (colBase < 256) {
#pragma unroll
    for (int i = 0; i < 4; ++i) {
      int rb = rowBase + wr * 64 + i * 16 + q * 4;
#pragma unroll
      for (int j = 0; j < 4; ++j) {
        int col = colBase + wc * 64 + j * 16 + fr;
        f32x4 v = acc[i][j];
#pragma unroll
        for (int rr = 0; rr < 4; ++rr) {
          int r = rb + rr;
          if (r < rowEnd) feat_bf[(size_t)r * 256 + col] = f2bf(v[rr]);
        }
      }
    }
  } else {
    int cOff = colBase - 256;
#pragma unroll
    for (int i = 0; i < 4; ++i) {
      int rb = rowBase + wr * 64 + i * 16 + q * 4;
#pragma unroll
      for (int j = 0; j < 4; ++j) {
        int col = cOff + wc * 64 + j * 16 + fr;
        f32x4 v = acc[i][j];
#pragma unroll
        for (int rr = 0; rr < 4; ++rr) {
          int r = rb + rr;
          if (r < rowEnd) resval[(size_t)r * 256 + col] = v[rr];
        }
      }
    }
  }
}

// -------- ft_attn(bf16) = softmax(tanh(einsum), axis=g); col sum-sq ----------
__global__ __launch_bounds__(256) void attn_probs(
    const unsigned short* __restrict__ feat_bf, const float* __restrict__ W_prob,
    unsigned short* __restrict__ ft_attn, float* __restrict__ col_ss, int N) {
  __shared__ float WL[8192];
  __shared__ float fsL[16 * 256];
  int tid = threadIdx.x;
  for (int i = tid; i < 8192; i += 256) WL[i] = W_prob[i];
  int nodeBase = blockIdx.x * 16;
  float ssp = 0.f;
  for (int i = 0; i < 16; ++i) {
    int n = nodeBase + i;
    float v = (n < N) ? __uint_as_float((unsigned)feat_bf[(size_t)n * 256 + tid] << 16) : 0.f;
    fsL[i * 256 + tid] = v;
    ssp += v * v;
  }
  atomicAdd(&col_ss[tid], ssp);
  __syncthreads();
  int h = tid >> 5, g = tid & 31;
  for (int i = 0; i < 16; ++i) {
    int n = nodeBase + i;
    if (n >= N) break;
    float t = 0.f;
    const float* wp = &WL[h * 1024 + g];
    const float* fr = &fsL[i * 256 + h * 32];
#pragma unroll
    for (int f = 0; f < 32; ++f) t = fmaf(fr[f], wp[f * 32], t);
    t = tanhf(t);
    float mx = t;
#pragma unroll
    for (int s = 16; s >= 1; s >>= 1) mx = fmaxf(mx, __shfl_xor(mx, s));
    float ex = __expf(t - mx);
    float sm = ex;
#pragma unroll
    for (int s = 16; s >= 1; s >>= 1) sm += __shfl_xor(sm, s);
    ft_attn[(size_t)n * 256 + tid] = f2bf(ex / sm);
  }
}

// --------------- scan stage 1: per-block (512) exclusive scan ----------------
__global__ __launch_bounds__(512) void scan_block(const int* __restrict__ deg,
                                                  int* __restrict__ start,
                                                  int* __restrict__ bsum, int n) {
  __shared__ int buf[512];
  int tid = threadIdx.x;
  int gid = blockIdx.x * 512 + tid;
  int v = (gid < n) ? deg[gid] : 0;
  buf[tid] = v;
  __syncthreads();
  for (int off = 1; off < 512; off <<= 1) {
    int t = (tid >= off) ? buf[tid - off] : 0;
    __syncthreads();
    buf[tid] += t;
    __syncthreads();
  }
  if (gid < n) start[gid] = buf[tid] - v;
  if (tid == 511) bsum[blockIdx.x] = buf[511];
}

// --------------- finalize col norms + scan stage 2 (one block) ---------------
__global__ __launch_bounds__(256) void mid_small(float* __restrict__ col_ss,
                                                 int* __restrict__ bsum, int nb) {
  int tid = threadIdx.x;
  col_ss[tid] = 1.f / fmaxf(sqrtf(col_ss[tid]), 1e-12f);
  __shared__ int buf[128];
  if (tid < nb) buf[tid] = bsum[tid];
  __syncthreads();
  if (tid == 0) {
    int run = 0;
    for (int i = 0; i < nb; ++i) { int v = buf[i]; buf[i] = run; run += v; }
  }
  __syncthreads();
  if (tid < nb) bsum[tid] = buf[tid];
}

// --------------- fill CSR + inline sim (8 lanes/edge) ------------------------
__global__ __launch_bounds__(256) void fill_sim(
    const int* __restrict__ src, const int* __restrict__ dst,
    const int* __restrict__ e_feat, const float* __restrict__ etype_attn,
    const unsigned short* __restrict__ slt,
    const float* __restrict__ inv_s, const float* __restrict__ inv_t,
    const int* __restrict__ start, const int* __restrict__ bsum,
    int* __restrict__ cursor, int* __restrict__ csr_src,
    float* __restrict__ csr_w, int E) {
  int tid = threadIdx.x;
  int j = tid & 7;
  int e = blockIdx.x * 32 + (tid >> 3);
  if (e >= E) return;
  int s = src[e], d = dst[e];
  const unsigned short* ps = slt + (size_t)s * 64 + j * 4;
  const unsigned short* pd = slt + (size_t)d * 64 + j * 4;
  uint2 sa = *reinterpret_cast<const uint2*>(ps);
  uint2 sb = *reinterpret_cast<const uint2*>(pd);
  uint2 ta = *reinterpret_cast<const uint2*>(ps + 32);
  uint2 tb = *reinterpret_cast<const uint2*>(pd + 32);
  float cs = bflo(sa.x) * bflo(sb.x) + bfhi(sa.x) * bfhi(sb.x) +
             bflo(sa.y) * bflo(sb.y) + bfhi(sa.y) * bfhi(sb.y);
  float ct = bflo(ta.x) * bflo(tb.x) + bfhi(ta.x) * bfhi(tb.x) +
             bflo(ta.y) * bflo(tb.y) + bfhi(ta.y) * bfhi(tb.y);
#pragma unroll
  for (int m = 4; m >= 1; m >>= 1) {
    cs += __shfl_xor(cs, m);
    ct += __shfl_xor(ct, m);
  }
  if (j == 0) {
    cs *= inv_s[s] * inv_s[d];
    ct *= inv_t[s] * inv_t[d];
    float sim = (0.4f * cs + 0.6f * ct + 1.f) * 0.5f;
    float wv = sim * etype_attn[e_feat[e]];
    int pos = start[d] + bsum[d >> 9] + atomicAdd(&cursor[d], 1);
    csr_src[pos] = s;
    csr_w[pos] = wv;
  }
}

// --------------- main: one wave per dst node, pipelined, no-max softmax ------
#define GATHER(S, FP, SL, TP)                                                  \
  {                                                                            \
    FP = *reinterpret_cast<const uint2*>(feat_bf + (size_t)(S) * 256 + fb);    \
    const unsigned short* sp_ = slt + (size_t)(S) * 64 + db;                   \
    SL = *reinterpret_cast<const uint2*>(sp_);                                 \
    TP = *reinterpret_cast<const uint2*>(sp_ + 32);                            \
  }

#define CONSUME(FP, SL, TP, WV)                                                \
  {                                                                            \
    float fs0 = bflo(FP.x), fs1 = bfhi(FP.x);                                  \
    float fs2 = bflo(FP.y), fs3 = bfhi(FP.y);                                  \
    float pa = ai4.x * fs0 + ai4.y * fs1 + ai4.z * fs2 + ai4.w * fs3;          \
    pa += __shfl_xor(pa, 1);                                                   \
    pa += __shfl_xor(pa, 2);                                                   \
    pa += __shfl_xor(pa, 4);                                                   \
    float p = __expf(pa * WV);                                                 \
    l += p;                                                                    \
    accf.x = fmaf(p, fs0, accf.x); accf.y = fmaf(p, fs1, accf.y);              \
    accf.z = fmaf(p, fs2, accf.z); accf.w = fmaf(p, fs3, accf.w);              \
    accs.x = fmaf(p, bflo(SL.x), accs.x); accs.y = fmaf(p, bfhi(SL.x), accs.y);\
    accs.z = fmaf(p, bflo(SL.y), accs.z); accs.w = fmaf(p, bfhi(SL.y), accs.w);\
    acct.x = fmaf(p, bflo(TP.x), acct.x); acct.y = fmaf(p, bfhi(TP.x), acct.y);\
    acct.z = fmaf(p, bflo(TP.y), acct.z); acct.w = fmaf(p, bfhi(TP.y), acct.w);\
  }

__global__ __launch_bounds__(256) void edge_aggregate(
    const unsigned short* __restrict__ feat_bf, const float* __restrict__ resval,
    const unsigned short* __restrict__ ft_attn, const float* __restrict__ inv_cn,
    const unsigned short* __restrict__ slt,
    const float* __restrict__ sloc, const float* __restrict__ topo,
    const int* __restrict__ start, const int* __restrict__ bsum,
    const int* __restrict__ deg,
    const int* __restrict__ csr_src, const float* __restrict__ csr_w,
    float* __restrict__ out, int N) {
  int wave = threadIdx.x >> 6;
  int n = blockIdx.x * 4 + wave;
  if (n >= N) return;
  int lane = threadIdx.x & 63;
  int j = lane & 7;
  int fb = (lane >> 3) * 32 + j * 4;
  int db = j * 4;

  uint2 at2 = *reinterpret_cast<const uint2*>(ft_attn + (size_t)n * 256 + fb);
  float4 icn4 = *reinterpret_cast<const float4*>(inv_cn + fb);
  float4 ai4 = make_float4(bflo(at2.x) * icn4.x, bfhi(at2.x) * icn4.y,
                           bflo(at2.y) * icn4.z, bfhi(at2.y) * icn4.w);
  float l = 0.f;
  float4 accf = make_float4(0.f, 0.f, 0.f, 0.f);
  float4 accs = make_float4(0.f, 0.f, 0.f, 0.f);
  float4 acct = make_float4(0.f, 0.f, 0.f, 0.f);
  int s0 = start[n] + bsum[n >> 9];
  int dg = deg[n];

  int sA = 0, sB = 0;
  float wA = 0.f, wB = 0.f;
  uint2 fpA, slA, tpA, fpB, slB, tpB;
  fpA = fpB = slA = slB = tpA = tpB = make_uint2(0u, 0u);
  if (dg > 0) {
    sA = csr_src[s0]; wA = csr_w[s0];
    GATHER(sA, fpA, slA, tpA);
  }
  if (dg > 1) {
    sB = csr_src[s0 + 1]; wB = csr_w[s0 + 1];
    GATHER(sB, fpB, slB, tpB);
  }
  int i = 0;
  for (; i + 1 < dg; i += 2) {
    CONSUME(fpA, slA, tpA, wA);
    if (i + 2 < dg) {
      sA = csr_src[s0 + i + 2]; wA = csr_w[s0 + i + 2];
      GATHER(sA, fpA, slA, tpA);
    }
    CONSUME(fpB, slB, tpB, wB);
    if (i + 3 < dg) {
      sB = csr_src[s0 + i + 3]; wB = csr_w[s0 + i + 3];
      GATHER(sB, fpB, slB, tpB);
    }
  }
  if (i < dg) CONSUME(fpA, slA, tpA, wA);

  float invl = (l > 0.f) ? 1.f / l : 0.f;

  float4 res4 = *reinterpret_cast<const float4*>(resval + (size_t)n * 256 + fb);
  float4 of = make_float4(fmaxf(fmaf(accf.x, invl, res4.x), 0.f),
                          fmaxf(fmaf(accf.y, invl, res4.y), 0.f),
                          fmaxf(fmaf(accf.z, invl, res4.z), 0.f),
                          fmaxf(fmaf(accf.w, invl, res4.w), 0.f));
  float4 os = make_float4(accs.x * invl, accs.y * invl, accs.z * invl, accs.w * invl);
  float4 ot = make_float4(acct.x * invl, acct.y * invl, acct.z * invl, acct.w * invl);
#pragma unroll
  for (int msk = 8; msk <= 32; msk <<= 1) {
    of.x += __shfl_xor(of.x, msk); of.y += __shfl_xor(of.y, msk);
    of.z += __shfl_xor(of.z, msk); of.w += __shfl_xor(of.w, msk);
    os.x += __shfl_xor(os.x, msk); os.y += __shfl_xor(os.y, msk);
    os.z += __shfl_xor(os.z, msk); os.w += __shfl_xor(os.w, msk);
    ot.x += __shfl_xor(ot.x, msk); ot.y += __shfl_xor(ot.y, msk);
    ot.z += __shfl_xor(ot.z, msk); ot.w += __shfl_xor(ot.w, msk);
  }
  if (lane < 8) {
    float4 sln = *reinterpret_cast<const float4*>(sloc + (size_t)n * 32 + db);
    float4 tpn = *reinterpret_cast<const float4*>(topo + (size_t)n * 32 + db);
    float4 o0 = make_float4(of.x * 0.125f, of.y * 0.125f, of.z * 0.125f, of.w * 0.125f);
    float4 o1 = make_float4(fmaf(os.x, 0.125f, sln.x), fmaf(os.y, 0.125f, sln.y),
                            fmaf(os.z, 0.125f, sln.z), fmaf(os.w, 0.125f, sln.w));
    float4 o2 = make_float4(fmaf(ot.x, 0.125f, tpn.x), fmaf(ot.y, 0.125f, tpn.y),
                            fmaf(ot.z, 0.125f, tpn.z), fmaf(ot.w, 0.125f, tpn.w));
    *reinterpret_cast<float4*>(out + (size_t)n * 32 + db) = o0;
    *reinterpret_cast<float4*>(out + (size_t)N * 32 + (size_t)n * 32 + db) = o1;
    *reinterpret_cast<float4*>(out + (size_t)2 * N * 32 + (size_t)n * 32 + db) = o2;
  }
}

extern "C" void kernel_launch(void* const* d_in, const int* in_sizes, int n_in,
                              void* d_out, int out_size, void* d_ws, size_t ws_size,
                              hipStream_t stream) {
  const float* feat = (const float*)d_in[0];
  const float* sloc = (const float*)d_in[1];
  const float* topo = (const float*)d_in[2];
  const int* src = (const int*)d_in[3];
  const int* dst = (const int*)d_in[4];
  const int* e_feat = (const int*)d_in[5];
  const float* W_proj0 = (const float*)d_in[6];
  const float* W_proj1 = (const float*)d_in[7];
  const float* W_prob = (const float*)d_in[8];
  const float* W_res0 = (const float*)d_in[9];
  const float* W_res1 = (const float*)d_in[10];
  const float* etype_attn = (const float*)d_in[11];
  int E = in_sizes[3];
  int N = in_sizes[1] / 32;
  float* out = (float*)d_out;

  char* ws = (char*)d_ws;
  size_t off = 0;
  auto alloc = [&](size_t bytes) -> char* {
    char* p = ws + off;
    off += (bytes + 255) & ~(size_t)255;
    return p;
  };
  // contiguous zero-init group: deg | cursor | col_ss
  int* deg = (int*)alloc((size_t)N * 4);
  int* cursor = (int*)alloc((size_t)N * 4);
  float* col_ss = (float*)alloc(256 * 4);
  size_t zeroBytes = ((char*)col_ss + 256 * 4) - (char*)deg;
  int* startArr = (int*)alloc(((size_t)N + 1) * 4);
  int* bsum = (int*)alloc(128 * 4);
  float* inv_s = (float*)alloc((size_t)N * 4);
  float* inv_t = (float*)alloc((size_t)N * 4);
  int* csr_src = (int*)alloc((size_t)E * 4);
  float* csr_w = (float*)alloc((size_t)E * 4);
  unsigned short* feat_bf = (unsigned short*)alloc((size_t)N * 256 * 2);
  unsigned short* slt = (unsigned short*)alloc((size_t)N * 64 * 2);
  float* resval = (float*)alloc((size_t)N * 256 * 4);
  unsigned short* ft_attn = (unsigned short*)alloc((size_t)N * 256 * 2);
  unsigned short* BTw = (unsigned short*)alloc((size_t)2 * 512 * 256 * 2);

  hipMemsetAsync(deg, 0, zeroBytes, stream);

  int nodeBlocks = (N + 7) / 8;
  int degBlocks = (E + 255) / 256;
  prep<<<1024 + nodeBlocks + degBlocks, 256, 0, stream>>>(
      W_proj0, W_res0, W_proj1, W_res1, BTw, sloc, topo, inv_s, inv_t, slt,
      dst, deg, N, E);

  int g0t = (HN0 + BM - 1) / BM;
  int g1t = (N - HN0 + BM - 1) / BM;
  gemm_mfma<<<dim3(g0t + g1t, 4), 256, 0, stream>>>(feat, BTw, feat_bf, resval, N);

  attn_probs<<<(N + 15) / 16, 256, 0, stream>>>(feat_bf, W_prob, ft_attn, col_ss, N);

  int nb = (N + 511) / 512;
  scan_block<<<nb, 512, 0, stream>>>(deg, startArr, bsum, N);
  mid_small<<<1, 256, 0, stream>>>(col_ss, bsum, nb);

  fill_sim<<<(E + 31) / 32, 256, 0, stream>>>(src, dst, e_feat, etype_attn, slt,
                                              inv_s, inv_t, startArr, bsum,
                                              cursor, csr_src, csr_w, E);

  edge_aggregate<<<(N + 3) / 4, 256, 0, stream>>>(feat_bf, resval, ft_attn, col_ss,
                                                  slt, sloc, topo, startArr, bsum, deg,
                                                  csr_src, csr_w, out, N);
}